// Round 11
// baseline (366.995 us; speedup 1.0000x reference)
//
#include <hip/hip_runtime.h>
#include <cstdint>
#include <cstddef>

// CausalAttention B=4 S=2048 D=1024.
// d_out = [context (4*2048*1024 f32)] ++ [attn_scores (4*2048*2048 f32)]
//
// scores = x M x^T, M[d,e] = sum_i Wq[d,i] Wk[e,i]:
//   M^T = bt(A=Wk, B=Wq)   (split bf16 3-pass; mu fused via atomics)
//   N~  = x M - sq*mu^T    (split; mean-deflated)
//   S   = N~ x^T + sq*u    (split, lower-tri; exact f32 rank-1 add-back)
// Round-20 (resubmit; r10 bench was a GPU-acquisition timeout):
// r9 ctx swizzle +3.5us (357.0 best). Structural insight from r8's
// failure: VGPR (88+64 AGPR = 152/thr) allows 12 waves/CU but the
// 512-thread block granularity strands 4 -> 8 waves, no cross-block TLP.
// m97's proven geometry (874-912 TF) is 128^2 tile / 256-thread block /
// SINGLE-buffer 32KB LDS / 2 barriers/K-step at ~3 blocks/CU. This round
// ports sv+n to that: split_core4/single_core4 (4 waves as 2x2, per-wave
// 64x64, same verified swizzle), __launch_bounds__(256,3). sv = 768
// persistent blocks over 1056 items (544 tri score + 512 V tiles);
// n = 512 blocks = exact 2/CU. ctx/softmax/m_cvtx unchanged from r9.

#define S_LEN 2048
#define D_DIM 1024
#define NBATCH 4
#define MEG (1024 * 1024)

typedef __attribute__((ext_vector_type(4))) float floatx4;
typedef __attribute__((ext_vector_type(8))) __bf16 bf16x8;
typedef __attribute__((ext_vector_type(8))) short short8v;

__device__ __forceinline__ unsigned short f2bf(float f) {
  union { float f; unsigned u; } v; v.f = f;
  unsigned r = v.u + 0x7FFF + ((v.u >> 16) & 1);   // round-to-nearest-even
  return (unsigned short)(r >> 16);
}
__device__ __forceinline__ float bf2f(unsigned short h) {
  union { unsigned u; float f; } v; v.u = ((unsigned)h) << 16; return v.f;
}

__device__ __forceinline__ void async_copy16(const void* g, void* l) {
  __builtin_amdgcn_global_load_lds(
      (const __attribute__((address_space(1))) void*)g,
      (__attribute__((address_space(3))) void*)l, 16, 0, 0);
}

#define VMCNT0() asm volatile("s_waitcnt vmcnt(0)" ::: "memory")
#define RAW_BAR() __builtin_amdgcn_s_barrier()
#define MFMA_BF16 __builtin_amdgcn_mfma_f32_16x16x32_bf16

// ====== 256-thread, 128x128-tile single-buffer cores (BK=32, m97 geom) ======
// 4 waves as 2(M)x2(N); per-wave 64x64 (4x4 frags of 16x16).
// LDS swizzle (verified, conflicts=0): LDS[row][v] holds
// global[row][v ^ ((row>>1)&3)] (16B units); staged via pre-swizzled global
// source (dest linear for global_load_lds), read back with the same XOR.
// Single 32KB buffer; {stage, syncthreads, reads+MFMA, syncthreads};
// per-K-step drain hidden by ~3 co-resident blocks/CU (m97/m114 TLP).

__device__ __forceinline__ void split_core4(
    const short* __restrict__ Ah, const short* __restrict__ Al,
    const short* __restrict__ Bh, const short* __restrict__ Bl,
    int lda, int ldb, int kIters, int blockM, int blockN,
    short (*AsH)[32], short (*AsL)[32],
    short (*BsH)[32], short (*BsL)[32],
    floatx4 (&acc)[4][4])
{
  const int tid  = threadIdx.x;          // 0..255
  const int lane = tid & 63;
  const int wave = tid >> 6;             // 0..3
  const int wm = (wave >> 1) * 64;       // 0,64
  const int wn = (wave & 1) * 64;        // 0,64
  const int fm = lane & 15;
  const int fu = lane >> 4;              // 16B unit 0..3

  int rA[4], sA[4], rB[4], sB[4];
  #pragma unroll
  for (int i = 0; i < 4; ++i) {
    rA[i] = wm + i * 16 + fm;
    sA[i] = (fu ^ ((rA[i] >> 1) & 3)) * 8;
    rB[i] = wn + i * 16 + fm;
    sB[i] = (fu ^ ((rB[i] >> 1) & 3)) * 8;
  }

  floatx4 zero = {0.f, 0.f, 0.f, 0.f};
  #pragma unroll
  for (int i = 0; i < 4; ++i)
    #pragma unroll
    for (int j = 0; j < 4; ++j)
      acc[i][j] = zero;

  const int r0 = tid >> 2;               // 0..63
  const int u0 = tid & 3;
  const int su = (u0 ^ ((r0 >> 1) & 3)) * 8;   // pre-swizzled source unit
  // rows r0 and r0+64 share ((row>>1)&3) (64/2=32, 32%4==0) -> same su
  const size_t a0 = (size_t)(blockM + r0) * lda + su;
  const size_t a1 = a0 + (size_t)64 * lda;
  const size_t b0 = (size_t)(blockN + r0) * ldb + su;
  const size_t b1 = b0 + (size_t)64 * ldb;

  for (int kt = 0; kt < kIters; ++kt) {
    const int kb = kt * 32;
    async_copy16(Ah + a0 + kb, &AsH[r0][u0 * 8]);
    async_copy16(Ah + a1 + kb, &AsH[r0 + 64][u0 * 8]);
    async_copy16(Al + a0 + kb, &AsL[r0][u0 * 8]);
    async_copy16(Al + a1 + kb, &AsL[r0 + 64][u0 * 8]);
    async_copy16(Bh + b0 + kb, &BsH[r0][u0 * 8]);
    async_copy16(Bh + b1 + kb, &BsH[r0 + 64][u0 * 8]);
    async_copy16(Bl + b0 + kb, &BsL[r0][u0 * 8]);
    async_copy16(Bl + b1 + kb, &BsL[r0 + 64][u0 * 8]);
    __syncthreads();   // drain loads; all waves staged

    bf16x8 bh[4], bl[4], ah[4], al[4];
    #pragma unroll
    for (int j = 0; j < 4; ++j) {
      bh[j] = *(const bf16x8*)(&BsH[rB[j]][sB[j]]);
      bl[j] = *(const bf16x8*)(&BsL[rB[j]][sB[j]]);
    }
    #pragma unroll
    for (int i = 0; i < 4; ++i) {
      ah[i] = *(const bf16x8*)(&AsH[rA[i]][sA[i]]);
      al[i] = *(const bf16x8*)(&AsL[rA[i]][sA[i]]);
    }
    __builtin_amdgcn_s_setprio(1);
    #pragma unroll
    for (int i = 0; i < 4; ++i)
      #pragma unroll
      for (int j = 0; j < 4; ++j) {
        acc[i][j] = MFMA_BF16(ah[i], bh[j], acc[i][j], 0, 0, 0);
        acc[i][j] = MFMA_BF16(ah[i], bl[j], acc[i][j], 0, 0, 0);
        acc[i][j] = MFMA_BF16(al[i], bh[j], acc[i][j], 0, 0, 0);
      }
    __builtin_amdgcn_s_setprio(0);
    __syncthreads();   // all reads done -> buffer free for next stage
  }
}

__device__ __forceinline__ void single_core4(
    const short* __restrict__ A, const short* __restrict__ B,
    int lda, int ldb, int kIters, int blockM, int blockN,
    short (*As)[32], short (*Bs)[32], floatx4 (&acc)[4][4])
{
  const int tid  = threadIdx.x;
  const int lane = tid & 63;
  const int wave = tid >> 6;
  const int wm = (wave >> 1) * 64;
  const int wn = (wave & 1) * 64;
  const int fm = lane & 15;
  const int fu = lane >> 4;

  int rA[4], sA[4], rB[4], sB[4];
  #pragma unroll
  for (int i = 0; i < 4; ++i) {
    rA[i] = wm + i * 16 + fm;
    sA[i] = (fu ^ ((rA[i] >> 1) & 3)) * 8;
    rB[i] = wn + i * 16 + fm;
    sB[i] = (fu ^ ((rB[i] >> 1) & 3)) * 8;
  }

  floatx4 zero = {0.f, 0.f, 0.f, 0.f};
  #pragma unroll
  for (int i = 0; i < 4; ++i)
    #pragma unroll
    for (int j = 0; j < 4; ++j)
      acc[i][j] = zero;

  const int r0 = tid >> 2;
  const int u0 = tid & 3;
  const int su = (u0 ^ ((r0 >> 1) & 3)) * 8;
  const size_t a0 = (size_t)(blockM + r0) * lda + su;
  const size_t a1 = a0 + (size_t)64 * lda;
  const size_t b0 = (size_t)(blockN + r0) * ldb + su;
  const size_t b1 = b0 + (size_t)64 * ldb;

  for (int kt = 0; kt < kIters; ++kt) {
    const int kb = kt * 32;
    async_copy16(A + a0 + kb, &As[r0][u0 * 8]);
    async_copy16(A + a1 + kb, &As[r0 + 64][u0 * 8]);
    async_copy16(B + b0 + kb, &Bs[r0][u0 * 8]);
    async_copy16(B + b1 + kb, &Bs[r0 + 64][u0 * 8]);
    __syncthreads();

    bf16x8 bfr[4], af[4];
    #pragma unroll
    for (int j = 0; j < 4; ++j)
      bfr[j] = *(const bf16x8*)(&Bs[rB[j]][sB[j]]);
    #pragma unroll
    for (int i = 0; i < 4; ++i)
      af[i] = *(const bf16x8*)(&As[rA[i]][sA[i]]);

    __builtin_amdgcn_s_setprio(1);
    #pragma unroll
    for (int i = 0; i < 4; ++i)
      #pragma unroll
      for (int j = 0; j < 4; ++j)
        acc[i][j] = MFMA_BF16(af[i], bfr[j], acc[i][j], 0, 0, 0);
    __builtin_amdgcn_s_setprio(0);
    __syncthreads();
  }
}

// ---------------- W conversions ----------------
// [0,512): Wq split. [512,1024): Wk split. [1024,2048): Wv transpose (hi only);
// block 1024 also zeroes muSum + the sv work-queue counter.

__global__ __launch_bounds__(256) void k_cvt_w(
    const float* __restrict__ wq, const float* __restrict__ wk,
    const float* __restrict__ wv,
    short* __restrict__ wqh, short* __restrict__ wql,
    short* __restrict__ wkh, short* __restrict__ wkl,
    short* __restrict__ wvt, float* __restrict__ muSum,
    int* __restrict__ cnt)
{
  const int bid = blockIdx.x;
  const int tid = threadIdx.x;
  if (bid < 1024) {
    const float4* src;
    short *dh, *dl;
    size_t idx;
    if (bid < 512) {
      idx = (size_t)bid * 256 + tid;
      src = (const float4*)wq; dh = wqh; dl = wql;
    } else {
      idx = (size_t)(bid - 512) * 256 + tid;
      src = (const float4*)wk; dh = wkh; dl = wkl;
    }
    const float4 u4 = src[idx * 2];
    const float4 w4 = src[idx * 2 + 1];
    float f[8] = {u4.x, u4.y, u4.z, u4.w, w4.x, w4.y, w4.z, w4.w};
    short8v oh, ol;
    #pragma unroll
    for (int e = 0; e < 8; ++e) {
      const unsigned short h = f2bf(f[e]);
      oh[e] = (short)h;
      ol[e] = (short)f2bf(f[e] - bf2f(h));
    }
    *(short8v*)(dh + idx * 8) = oh;
    *(short8v*)(dl + idx * 8) = ol;
  } else {
    if (bid == 1024) {   // zero muSum + work queue before later kernels
      float4 z = {0.f, 0.f, 0.f, 0.f};
      ((float4*)muSum)[tid] = z;
      if (tid == 0) *cnt = 0;
    }
    const int rem = bid - 1024;
    const int bx = rem & 31, by = rem >> 5;
    const int tx = tid & 31, ty = tid >> 5;  // 32 x 8
    __shared__ float tile[32][33];
    const int colIn = bx * 32 + tx;
    #pragma unroll
    for (int i = 0; i < 4; ++i) {
      const int rowIn = by * 32 + ty + i * 8;
      tile[ty + i * 8][tx] = wv[(size_t)rowIn * D_DIM + colIn];
    }
    __syncthreads();
    const int colOut = by * 32 + tx;   // d (input row of Wv)
    #pragma unroll
    for (int i = 0; i < 4; ++i) {
      const int rowOut = bx * 32 + ty + i * 8;  // n (output col of Wv)
      wvt[(size_t)rowOut * D_DIM + colOut] = (short)f2bf(tile[tx][ty + i * 8]);
    }
  }
}

// ---------------- M^T GEMM (256 64x64 tiles, BK=64) + x split (4096), fused ----------------

__global__ __launch_bounds__(256) void k_m_cvtx(
    const short* __restrict__ wqh, const short* __restrict__ wql,
    const short* __restrict__ wkh, const short* __restrict__ wkl,
    short* __restrict__ mth, short* __restrict__ mtl,
    float* __restrict__ muSum,
    const float4* __restrict__ x,
    short* __restrict__ xh, short* __restrict__ xl)
{
  __shared__ alignas(16) short AsH[2][64][32];
  __shared__ alignas(16) short AsL[2][64][32];
  __shared__ alignas(16) short BsH[2][64][32];
  __shared__ alignas(16) short BsL[2][64][32];
  const int g = blockIdx.x;
  const int tid = threadIdx.x;

  if (g < 256) {
    // --- 64x64 M^T tile: A = Wk rows (e), B = Wq rows (d), inner = i ---
    floatx4 acc[2][2];
    const int blockM = (g >> 4) * 64;    // e
    const int blockN = (g & 15) * 64;    // d
    const int lane = tid & 63, wave = tid >> 6;
    const int wm = (wave >> 1) * 32, wn = (wave & 1) * 32;
    const int fm = lane & 15, fk = (lane >> 4) * 8;

    floatx4 zero = {0.f, 0.f, 0.f, 0.f};
    #pragma unroll
    for (int i = 0; i < 2; ++i)
      #pragma unroll
      for (int j = 0; j < 2; ++j)
        acc[i][j] = zero;

    const int sr = tid >> 2;             // row 0..63
    const int sc = (tid & 3) * 8;        // col 0..31 step 8
    const short* ah0 = wkh + (size_t)(blockM + sr) * D_DIM + sc;
    const short* al0 = wkl + (size_t)(blockM + sr) * D_DIM + sc;
    const short* bh0 = wqh + (size_t)(blockN + sr) * D_DIM + sc;
    const short* bl0 = wql + (size_t)(blockN + sr) * D_DIM + sc;
    short* ahB = &AsH[0][0][0]; short* alB = &AsL[0][0][0];
    short* bhB = &BsH[0][0][0]; short* blB = &BsL[0][0][0];
    const int l0 = tid * 8, l1 = (tid + 256) * 8;

    for (int kt = 0; kt < 16; ++kt) {    // BK=64
      const int kb = kt * 64;
      async_copy16(ah0 + kb, ahB + l0);
      async_copy16(ah0 + kb + 32, ahB + l1);
      async_copy16(al0 + kb, alB + l0);
      async_copy16(al0 + kb + 32, alB + l1);
      async_copy16(bh0 + kb, bhB + l0);
      async_copy16(bh0 + kb + 32, bhB + l1);
      async_copy16(bl0 + kb, blB + l0);
      async_copy16(bl0 + kb + 32, blB + l1);
      __syncthreads();
      #pragma unroll
      for (int ks = 0; ks < 2; ++ks) {
        bf16x8 ah[2], al[2], bh[2], bl[2];
        #pragma unroll
        for (int i = 0; i < 2; ++i) {
          ah[i] = *(const bf16x8*)(&AsH[ks][wm + i * 16 + fm][fk]);
          al[i] = *(const bf16x8*)(&AsL[ks][wm + i * 16 + fm][fk]);
        }
        #pragma unroll
        for (int j = 0; j < 2; ++j) {
          bh[j] = *(const bf16x8*)(&BsH[ks][wn + j * 16 + fm][fk]);
          bl[j] = *(const bf16x8*)(&BsL[ks][wn + j * 16 + fm][fk]);
        }
        #pragma unroll
        for (int i = 0; i < 2; ++i)
          #pragma unroll
          for (int j = 0; j < 2; ++j) {
            acc[i][j] = MFMA_BF16(ah[i], bh[j], acc[i][j], 0, 0, 0);
            acc[i][j] = MFMA_BF16(ah[i], bl[j], acc[i][j], 0, 0, 0);
            acc[i][j] = MFMA_BF16(al[i], bh[j], acc[i][j], 0, 0, 0);
          }
      }
      __syncthreads();
    }

    const int rb = wm + ((lane >> 4) << 2);
    const int cb = wn + (lane & 15);
    #pragma unroll
    for (int i = 0; i < 2; ++i)
      #pragma unroll
      for (int j = 0; j < 2; ++j) {
        const int n = blockN + cb + j * 16;
        #pragma unroll
        for (int r = 0; r < 2 * 2; ++r) {
          const int m = blockM + rb + i * 16 + r;
          const float f = acc[i][j][r];
          const unsigned short h = f2bf(f);
          mth[(size_t)m * D_DIM + n] = (short)h;
          mtl[(size_t)m * D_DIM + n] = (short)f2bf(f - bf2f(h));
        }
      }
    // mu partials: per row e, sum over this block's 64 d-cols
    #pragma unroll
    for (int i = 0; i < 2; ++i)
      #pragma unroll
      for (int r = 0; r < 4; ++r) {
        float v = acc[i][0][r] + acc[i][1][r];
        v += __shfl_xor(v, 1); v += __shfl_xor(v, 2);
        v += __shfl_xor(v, 4); v += __shfl_xor(v, 8);
        if ((lane & 15) == 0)
          atomicAdd(&muSum[blockM + rb + i * 16 + r], v);
      }
  } else {
    const size_t idx = (size_t)(g - 256) * 256 + tid;
    const float4 u4 = x[idx * 2];
    const float4 w4 = x[idx * 2 + 1];
    float f[8] = {u4.x, u4.y, u4.z, u4.w, w4.x, w4.y, w4.z, w4.w};
    short8v oh, ol;
    #pragma unroll
    for (int e = 0; e < 8; ++e) {
      const unsigned short h = f2bf(f[e]);
      oh[e] = (short)h;
      ol[e] = (short)f2bf(f[e] - bf2f(h));
    }
    *(short8v*)(xh + idx * 8) = oh;
    *(short8v*)(xl + idx * 8) = ol;
  }
}

// ---------------- per-row stats over reconstructed split-x ----------------

__global__ __launch_bounds__(256) void k_rowstats(
    const short* __restrict__ xh, const short* __restrict__ xl,
    const float* __restrict__ muSum, float* __restrict__ sq, float* __restrict__ u)
{
  const int r = blockIdx.x, tid = threadIdx.x;
  const ushort4 h = *(const ushort4*)(xh + (size_t)r * D_DIM + tid * 4);
  const ushort4 l = *(const ushort4*)(xl + (size_t)r * D_DIM + tid * 4);
  const float4 m4 = *(const float4*)(muSum + tid * 4);
  const float x0 = bf2f(h.x) + bf2f(l.x);
  const float x1 = bf2f(h.y) + bf2f(l.y);
  const float x2 = bf2f(h.z) + bf2f(l.z);
  const float x3 = bf2f(h.w) + bf2f(l.w);
  float s = x0 + x1 + x2 + x3;
  float uu = m4.x * x0 + m4.y * x1 + m4.z * x2 + m4.w * x3;
  #pragma unroll
  for (int off = 32; off > 0; off >>= 1) {
    s  += __shfl_xor(s, off);
    uu += __shfl_xor(uu, off);
  }
  __shared__ float ps[4], pu[4];
  if ((tid & 63) == 0) { ps[tid >> 6] = s; pu[tid >> 6] = uu; }
  __syncthreads();
  if (tid == 0) {
    sq[r] = ps[0] + ps[1] + ps[2] + ps[3];
    u[r]  = (pu[0] + pu[1] + pu[2] + pu[3]) * (1.0f / 1024.0f);
  }
}

// ---------------- N~ = x M - sq mu^T, 128^2 tiles, sb core, 2 blk/CU ----------------
// 512 blocks = exactly 2 blocks/CU (32KB LDS each).

__global__ __launch_bounds__(256, 3) void k_gemm_n4(
    const short* __restrict__ xh, const short* __restrict__ xl,
    const short* __restrict__ mth, const short* __restrict__ mtl,
    const float* __restrict__ sq, const float* __restrict__ muSum,
    short* __restrict__ nh, short* __restrict__ nl)
{
  __shared__ alignas(16) short AsH[128][32];
  __shared__ alignas(16) short AsL[128][32];
  __shared__ alignas(16) short BsH[128][32];
  __shared__ alignas(16) short BsL[128][32];
  floatx4 acc[4][4];
  const int g = blockIdx.x;
  const int swz = (g & 7) * 64 + (g >> 3);     // XCD-contiguous chunks
  const int blockM = (swz >> 3) * 128;         // global row (b,s)
  const int blockN = (swz & 7) * 128;          // e
  split_core4(xh, xl, mth, mtl, D_DIM, D_DIM, D_DIM / 32,
              blockM, blockN, AsH, AsL, BsH, BsL, acc);

  const int tid = threadIdx.x, lane = tid & 63, wave = tid >> 6;
  const int wm = (wave >> 1) * 64, wn = (wave & 1) * 64;
  const int rb = wm + ((lane >> 4) << 2);
  const int cb = wn + (lane & 15);
  #pragma unroll
  for (int i = 0; i < 4; ++i)
    #pragma unroll
    for (int j = 0; j < 4; ++j) {
      const int n = blockN + cb + j * 16;
      const float muv = muSum[n] * (1.0f / 1024.0f);
      #pragma unroll
      for (int r = 0; r < 4; ++r) {
        const int m = blockM + rb + i * 16 + r;
        const float f = acc[i][j][r] - sq[m] * muv;   // deflate
        const unsigned short h = f2bf(f);
        nh[(size_t)m * D_DIM + n] = (short)h;
        nl[(size_t)m * D_DIM + n] = (short)f2bf(f - bf2f(h));
      }
    }
}

// ---------------- fused scores + V, persistent 768-block work queue ----------------
// items 0..543: score tiles (128x128, lower-tri: b in [0,4), bi in [0,16),
//               bj in [0,bi+1); 136/batch — heavy, drained first)
// items 544..1055: V tiles (128x128 — light tail fillers)

__global__ __launch_bounds__(256, 3) void k_gemm_sv4(
    const short* __restrict__ nh, const short* __restrict__ nl,
    const short* __restrict__ xh, const short* __restrict__ xl,
    const float* __restrict__ sq, const float* __restrict__ u,
    const short* __restrict__ wvt, float* __restrict__ attn,
    short* __restrict__ vt, int* __restrict__ cnt)
{
  __shared__ alignas(16) short AsH[128][32];
  __shared__ alignas(16) short AsL[128][32];
  __shared__ alignas(16) short BsH[128][32];
  __shared__ alignas(16) short BsL[128][32];
  __shared__ int s_item;

  const int tid = threadIdx.x, lane = tid & 63, wave = tid >> 6;
  const int wm = (wave >> 1) * 64, wn = (wave & 1) * 64;
  const int rb = wm + ((lane >> 4) << 2);
  const int cb = wn + (lane & 15);

  for (;;) {
    if (tid == 0) s_item = atomicAdd(cnt, 1);
    __syncthreads();
    const int item = s_item;
    if (item >= 1056) return;    // block-uniform exit

    floatx4 acc[4][4];
    if (item < 544) {
      // scores: per batch, lower-tri tiles of 128x128: bj <= bi.
      const int b = item / 136;
      int t = item - b * 136;
      int bi = 0;
      while (t >= bi + 1) { t -= bi + 1; ++bi; }
      const int bj = t;

      const size_t boff = (size_t)b * S_LEN * D_DIM;
      split_core4(nh + boff, nl + boff, xh + boff, xl + boff,
                  D_DIM, D_DIM, D_DIM / 32, bi * 128, bj * 128,
                  AsH, AsL, BsH, BsL, acc);

      float* out = attn + (size_t)b * S_LEN * S_LEN;
      const int rowBase = (b << 11) + bi * 128;
      const int colBase = (b << 11) + bj * 128;
      #pragma unroll
      for (int j = 0; j < 4; ++j) {
        const int n = bj * 128 + cb + j * 16;
        const float uv = u[colBase + cb + j * 16];
        #pragma unroll
        for (int i = 0; i < 4; ++i)
          #pragma unroll
          for (int r = 0; r < 4; ++r) {
            const int m = bi * 128 + rb + i * 16 + r;
            const float sv = sq[rowBase + rb + i * 16 + r];
            out[(size_t)m * S_LEN + n] = acc[i][j][r] + sv * uv;  // raw
          }
      }
    } else {
      const int vb = item - 544;            // 0..511
      const int blockM = (vb >> 3) * 128;   // global row over 8192
      const int blockN = (vb & 7) * 128;    // d
      single_core4(xh, wvt, D_DIM, D_DIM, D_DIM / 32, blockM, blockN,
                   AsH, BsH, acc);
      #pragma unroll
      for (int i = 0; i < 4; ++i)
        #pragma unroll
        for (int j = 0; j < 4; ++j) {
          const int n = blockN + cb + j * 16;   // d index
          const int m0 = blockM + rb + i * 16;  // global row, 4-aligned
          const int b = m0 >> 11;
          const int s0 = m0 & (S_LEN - 1);
          ushort4 pk;
          pk.x = f2bf(acc[i][j][0]); pk.y = f2bf(acc[i][j][1]);
          pk.z = f2bf(acc[i][j][2]); pk.w = f2bf(acc[i][j][3]);
          *(ushort4*)(vt + ((size_t)b * D_DIM + n) * S_LEN + s0) = pk;
        }
    }
  }
}

// ---------------- softmax: prefix-only reads, band-limited pb writes ----------------

__global__ __launch_bounds__(256) void k_softmax(float* __restrict__ attn,
                                                 short* __restrict__ pb) {
  const int b = blockIdx.x >> 11;
  const int q = blockIdx.x & (S_LEN - 1);
  float* row  = attn + ((size_t)b * S_LEN + q) * S_LEN;
  short* prow = pb   + ((size_t)b * S_LEN + q) * S_LEN;
  const int tid = threadIdx.x;
  const int k0 = tid * 8;
  const int kBand = ((q >> 7) + 1) << 7;   // 128-aligned band end
  __shared__ float sMax[4], sSum[4];

  float v[8];
  if (k0 <= q) {               // load only the live prefix
    const float4 a0 = *(const float4*)(row + k0);
    const float4 a1 = *(const float4*)(row + k0 + 4);
    v[0] = a0.x; v[1] = a0.y; v[2] = a0.z; v[3] = a0.w;
    v[4] = a1.x; v[5] = a1.y; v[6] = a1.z; v[7] = a1.w;
  } else {
    #pragma unroll
    for (int e = 0; e < 8; ++e) v[e] = -3.0e38f;
  }

  float mx = -3.0e38f;
  #pragma unroll
  for (int e = 0; e < 8; ++e) {
    v[e] = (k0 + e <= q) ? v[e] : -3.0e38f;
    mx = fmaxf(mx, v[e]);
  }
  #pragma unroll
  for (int off = 32; off > 0; off >>= 1) mx = fmaxf(mx, __shfl_xor(mx, off));
  if ((tid & 63) == 0) sMax[tid >> 6] = mx;
  __syncthreads();
  mx = fmaxf(fmaxf(sMax[0], sMax[1]), fmaxf(sMax[2], sMax[3]));

  float s = 0.f;
  #pragma unroll
  for (int e = 0; e < 8; ++e) {
    const float p = (k0 + e <= q) ? __expf((v[e] - mx) * 0.03125f) : 0.f;
    v[e] = p;
    s += p;
  }
  #pragma unroll
  for (int off = 32; off > 0; off >>= 1) s += __shfl_xor(s, off);
  if ((tid & 63) == 0) sSum[tid >> 6] = s;
  __syncthreads();
  s = sSum[0] + sSum[1] + sSum[2] + sSum[3];
  const float inv = 1.0f / s;

  float o[8];
  #pragma unroll
  for (int e = 0; e < 8; ++e) o[e] = v[e] * inv;   // 0 for masked
  float4 w0 = {o[0], o[1], o[2], o[3]};
  float4 w1 = {o[4], o[5], o[6], o[7]};
  *(float4*)(row + k0) = w0;
  *(float4*)(row + k0 + 4) = w1;
  if (k0 < kBand) {
    ushort4 p0, p1;
    p0.x = f2bf(o[0]); p0.y = f2bf(o[1]); p0.z = f2bf(o[2]); p0.w = f2bf(o[3]);
    p1.x = f2bf(o[4]); p1.y = f2bf(o[5]); p1.z = f2bf(o[6]); p1.w = f2bf(o[7]);
    *(ushort4*)(prow + k0) = p0;
    *(ushort4*)(prow + k0 + 4) = p1;
  }
}

// ---------------- context = P @ V, 128^2, BK=64 k-plane LDS, swizzled ----------------
// T2 swizzle (rule 21, both-sides): source col unit pre-swizzled
// su = (u0 ^ ((r0>>1)&3))*8 with linear gload_lds dest; frag reads use
// the same XOR.

__global__ __launch_bounds__(256) void k_gemm_ctx(
    const short* __restrict__ pb, const short* __restrict__ vt,
    float* __restrict__ ctx)
{
  __shared__ alignas(16) short As2[2][128][32];
  __shared__ alignas(16) short Bs2[2][128][32];
  floatx4 acc[4][4];
  const int b = blockIdx.z;
  const int by = 15 - blockIdx.y;        // heavy K-loops dispatched first
  const int blockM = by * 128;           // q
  const int blockN = blockIdx.x * 128;   // d
  const int kIters = (by + 1) * 2;       // BK=64; k <= blockM+127 only
  const short* A = pb + (size_t)b * S_LEN * S_LEN;
  const short* B = vt + (size_t)b * D_DIM * S_LEN;

  const int tid = threadIdx.x, lane = tid & 63, wave = tid >> 6;
  const int wm = (wave >> 1) * 64, wn = (wave & 1) * 64;
  const int fm = lane & 15;
  const int fu = lane >> 4;

  int rA[4], sA[4], rB[4], sB[4];
  #pragma unroll
  for (int i = 0; i < 4; ++i) {
    rA[i] = wm + i * 16 + fm;
    sA[i] = (fu ^ ((rA[i] >> 1) & 3)) * 8;
    rB[i] = wn + i * 16 + fm;
    sB[i] = (fu ^ ((rB[i] >> 1) & 3)) * 8;
  }

  floatx4 zero = {0.f, 0.f, 0.f, 0.f};
  #pragma unroll
  for (int i = 0; i < 4; ++i)
    #pragma unroll
    for (int j = 0; j < 4; ++j)
      acc[i][j] = zero;

  const int r0 = tid >> 2;               // 0..63
  const int u0 = tid & 3;
  const int su = (u0 ^ ((r0 >> 1) & 3)) * 8;   // pre-swizzled source unit
  // rows r0 and r0+64 share ((row>>1)&3) (64/2 = 32, 32%4 == 0) -> same su
  const short* a0 = A + (size_t)(blockM + r0) * S_LEN + su;
  const short* a1 = a0 + (size_t)64 * S_LEN;
  const short* b0 = B + (size_t)(blockN + r0) * S_LEN + su;
  const short* b1 = b0 + (size_t)64 * S_LEN;
  short* asBase = &As2[0][0][0];
  short* bsBase = &Bs2[0][0][0];
  short* as0 = asBase + (size_t)tid * 8;             // [0][r0][u0*8]
  short* as1 = asBase + (size_t)(tid + 256) * 8;     // [0][r0+64][u0*8]
  short* as2 = asBase + (size_t)(tid + 512) * 8;     // [1][r0][u0*8]
  short* as3 = asBase + (size_t)(tid + 768) * 8;     // [1][r0+64][u0*8]
  short* bs0 = bsBase + (size_t)tid * 8;
  short* bs1 = bsBase + (size_t)(tid + 256) * 8;
  short* bs2 = bsBase + (size_t)(tid + 512) * 8;
  short* bs3 = bsBase + (size_t)(tid + 768) * 8;

  for (int kt = 0; kt < kIters; ++kt) {
    const int kb = kt * 64;
    async_copy16(a0 + kb, as0);
    async_copy16(a1 + kb, as1);
    async_copy16(a0 + kb + 32, as2);
    async_copy16(a1 + kb + 32, as3);
    async_copy16(b0 + kb, bs0);
    async_copy16(b1 + kb, bs1);
    async_copy16(b0 + kb + 32, bs2);
    async_copy16(b1 + kb + 32, bs3);
    __syncthreads();
    #pragma unroll
    for (int ks = 0; ks < 2; ++ks) {
      bf16x8 af[4], bfr[4];
      #pragma unroll
      for (int i = 0; i < 4; ++i)
        af[i] = *(const bf16x8*)(&As2[ks][rA[i]][sA[i]]);
      #pragma unroll
      for (int j = 0; j < 4; ++j)
        bfr[j] = *(const bf16x8*)(&Bs2[ks][rB[j]][sB[j]]);
      __builtin_amdgcn_s_setprio(1);
      #pragma unroll
      for (int i = 0; i < 4; ++i)
        #pragma unroll
        for (int j = 0; j < 4; ++j)
          acc[i][j] = MFMA_BF16(af[i], bfr[j], acc[i][j], 0, 0, 0);
      __builtin_amdgcn_s_setprio(0);
    }
    __syncthreads();
  }

  float* out = ctx + (size_t)b * S_LEN * D_DIM;
  const int rb = wm + ((lane >> 4) << 2);
  const int cb = wn + (lane & 15);
  #pragma unroll
  for (int i = 0; i < 4; ++i)
    #pragma unroll
    for (int j = 0; j < 4; ++j) {
      const int n = blockN + cb + j * 16;
      #pragma unroll
      for (int r = 0; r < 4; ++r) {
        const int m = blockM + rb + i * 16 + r;
        out[(size_t)m * D_DIM + n] = acc[i][j][r];
      }
    }
}

// ---------------- launch ----------------

extern "C" void kernel_launch(void* const* d_in, const int* in_sizes, int n_in,
                              void* d_out, int out_size, void* d_ws, size_t ws_size,
                              hipStream_t stream) {
  const float* x  = (const float*)d_in[0];
  const float* wq = (const float*)d_in[1];
  const float* wk = (const float*)d_in[2];
  const float* wv = (const float*)d_in[3];

  float* out  = (float*)d_out;
  float* ctx  = out;                                       // [4,2048,1024]
  float* attn = out + (size_t)NBATCH * S_LEN * D_DIM;      // [4,2048,2048]

  // workspace (shorts), ~94 MiB; pb aliases nh/nl (dead after scores GEMM)
  short* ws  = (short*)d_ws;
  short* xh  = ws;                                  // 8M
  short* xl  = xh + (size_t)8 * MEG;                // 8M
  short* wqh = xl + (size_t)8 * MEG;                // 1M Wq hi (original layout)
  short* wql = wqh + (size_t)1 * MEG;               // 1M Wq lo
  short* wkh = wql + (size_t)1 * MEG;               // 1M Wk hi
  short* wkl = wkh + (size_t)1 * MEG;               // 1M Wk lo
  short* wvt = wkl + (size_t)1 * MEG;               // 1M Wv^T hi
  short* mth = wvt + (size_t)1 * MEG;               // 1M M^T hi
  short* mtl = mth + (size_t)1 * MEG;               // 1M M^T lo
  short* nh  = mtl + (size_t)1 * MEG;               // 8M N~ hi
  short* nl  = nh + (size_t)8 * MEG;                // 8M N~ lo
  short* vt  = nl + (size_t)8 * MEG;                // 8M V^T [b,d,s]
  short* pb  = nh;                                  // 16M alias (nh+nl)
  float* fb  = (float*)(vt + (size_t)8 * MEG);
  float* muS = fb;                                  // 1024 (sum over d, not mean)
  float* sq  = fb + 1024;                           // 8192
  float* u   = sq + 8192;                           // 8192
  int*   cnt = (int*)(u + 8192);                    // sv work-queue counter

  k_cvt_w<<<2048, 256, 0, stream>>>(wq, wk, wv, wqh, wql, wkh, wkl, wvt,
                                    muS, cnt);
  k_m_cvtx<<<4352, 256, 0, stream>>>(wqh, wql, wkh, wkl, mth, mtl, muS,
                                     (const float4*)x, xh, xl);
  k_rowstats<<<8192, 256, 0, stream>>>(xh, xl, muS, sq, u);
  k_gemm_n4<<<512, 256, 0, stream>>>(xh, xl, mth, mtl, sq, muS, nh, nl);
  k_gemm_sv4<<<768, 256, 0, stream>>>(nh, nl, xh, xl, sq, u, wvt, attn,
                                      vt, cnt);
  k_softmax<<<NBATCH * S_LEN, 256, 0, stream>>>(attn, pb);
  k_gemm_ctx<<<dim3(8, 16, 4), 256, 0, stream>>>(pb, vt, ctx);
}

// Round 13
// 353.751 us; speedup vs baseline: 1.0374x; 1.0374x over previous
//
#include <hip/hip_runtime.h>
#include <cstdint>
#include <cstddef>

// CausalAttention B=4 S=2048 D=1024.
// d_out = [context (4*2048*1024 f32)] ++ [attn_scores (4*2048*2048 f32)]
//
// scores = x M x^T, M[d,e] = sum_i Wq[d,i] Wk[e,i]:
//   M^T = bt(A=Wk, B=Wq)   (split bf16 3-pass; mu fused via atomics)
//   N~  = x M - sq*mu^T    (split; mean-deflated)
//   S   = N~ x^T + sq*u    (split, lower-tri; exact f32 rank-1 add-back)
// Round-23 (resubmit of r9-exact; r12 bench was a GPU-acquisition
// timeout). r9 measured 356.96us (session best): 256x128-dbuf 2-phase
// cores + T2 swizzle everywhere (conflicts=0) + persistent LPT queue in
// sv8 + swizzled ctx. Ledger: schedule micro-opts null-to-negative
// (r2/r4/r5/r6), single-buffer occupancy -21us (r8: VGPR-bound), small-
// tile occupancy -10us (r11: FETCH x2.4 L2 thrash). This is the measured
// optimum of the structure family.

#define S_LEN 2048
#define D_DIM 1024
#define NBATCH 4
#define MEG (1024 * 1024)

typedef __attribute__((ext_vector_type(4))) float floatx4;
typedef __attribute__((ext_vector_type(8))) __bf16 bf16x8;
typedef __attribute__((ext_vector_type(8))) short short8v;

__device__ __forceinline__ unsigned short f2bf(float f) {
  union { float f; unsigned u; } v; v.f = f;
  unsigned r = v.u + 0x7FFF + ((v.u >> 16) & 1);   // round-to-nearest-even
  return (unsigned short)(r >> 16);
}
__device__ __forceinline__ float bf2f(unsigned short h) {
  union { unsigned u; float f; } v; v.u = ((unsigned)h) << 16; return v.f;
}

__device__ __forceinline__ void async_copy16(const void* g, void* l) {
  __builtin_amdgcn_global_load_lds(
      (const __attribute__((address_space(1))) void*)g,
      (__attribute__((address_space(3))) void*)l, 16, 0, 0);
}

#define VMCNT0() asm volatile("s_waitcnt vmcnt(0)" ::: "memory")
#define RAW_BAR() __builtin_amdgcn_s_barrier()
#define MFMA_BF16 __builtin_amdgcn_mfma_f32_16x16x32_bf16

// ============ 512-thread, 256x128-tile phased cores (BK=32, dbuf) ============
// 8 waves as 4(M)x2(N); per-wave 64x64 (4x4 frags of 16x16).
// LDS swizzle (verified, conflicts=0): LDS[row][v] holds
// global[row][v ^ ((row>>1)&3)] (16B units); staged via pre-swizzled global
// source (dest linear for global_load_lds), read back with the same XOR.
// 2-phase schedule — best measured (105us sv8, 29% MfmaUtil).

__device__ __forceinline__ void split_core8(
    const short* __restrict__ Ah, const short* __restrict__ Al,
    const short* __restrict__ Bh, const short* __restrict__ Bl,
    int lda, int ldb, int kIters, int blockM, int blockN,
    short (*AsH)[256][32], short (*AsL)[256][32],
    short (*BsH)[128][32], short (*BsL)[128][32],
    floatx4 (&acc)[4][4])
{
  const int tid  = threadIdx.x;          // 0..511
  const int lane = tid & 63;
  const int wave = tid >> 6;             // 0..7
  const int wm = (wave >> 1) * 64;       // 0,64,128,192
  const int wn = (wave & 1) * 64;        // 0,64
  const int fm = lane & 15;
  const int fu = lane >> 4;              // 16B unit 0..3

  int rA[4], sA[4], rB[4], sB[4];
  #pragma unroll
  for (int i = 0; i < 4; ++i) {
    rA[i] = wm + i * 16 + fm;
    sA[i] = (fu ^ ((rA[i] >> 1) & 3)) * 8;
    rB[i] = wn + i * 16 + fm;
    sB[i] = (fu ^ ((rB[i] >> 1) & 3)) * 8;
  }

  floatx4 zero = {0.f, 0.f, 0.f, 0.f};
  #pragma unroll
  for (int i = 0; i < 4; ++i)
    #pragma unroll
    for (int j = 0; j < 4; ++j)
      acc[i][j] = zero;

  const int r0 = tid >> 2;               // 0..127
  const int u0 = tid & 3;
  const int su = (u0 ^ ((r0 >> 1) & 3)) * 8;   // pre-swizzled source unit
  const size_t a0 = (size_t)(blockM + r0) * lda + su;
  const size_t a1 = a0 + (size_t)128 * lda;
  const size_t b0 = (size_t)(blockN + r0) * ldb + su;

  auto stage0 = [&](int bf, int kb) {
    async_copy16(Ah + a0 + kb, &AsH[bf][r0][u0 * 8]);
    async_copy16(Al + a0 + kb, &AsL[bf][r0][u0 * 8]);
    async_copy16(Bh + b0 + kb, &BsH[bf][r0][u0 * 8]);
  };
  auto stage1 = [&](int bf, int kb) {
    async_copy16(Ah + a1 + kb, &AsH[bf][r0 + 128][u0 * 8]);
    async_copy16(Al + a1 + kb, &AsL[bf][r0 + 128][u0 * 8]);
    async_copy16(Bl + b0 + kb, &BsL[bf][r0][u0 * 8]);
  };

  stage0(0, 0);
  stage1(0, 0);
  VMCNT0();
  RAW_BAR();

  for (int kt = 0; kt < kIters; ++kt) {
    const int cur = kt & 1;
    const int kb = (kt + 1) * 32;
    const bool pf = (kt + 1) < kIters;

    // ---- phase 0: B frags + A rows i=0,1; 24 MFMA ----
    bf16x8 bh[4], bl[4];
    #pragma unroll
    for (int j = 0; j < 4; ++j) {
      bh[j] = *(const bf16x8*)(&BsH[cur][rB[j]][sB[j]]);
      bl[j] = *(const bf16x8*)(&BsL[cur][rB[j]][sB[j]]);
    }
    bf16x8 ah0 = *(const bf16x8*)(&AsH[cur][rA[0]][sA[0]]);
    bf16x8 al0 = *(const bf16x8*)(&AsL[cur][rA[0]][sA[0]]);
    bf16x8 ah1 = *(const bf16x8*)(&AsH[cur][rA[1]][sA[1]]);
    bf16x8 al1 = *(const bf16x8*)(&AsL[cur][rA[1]][sA[1]]);
    if (pf) stage0(cur ^ 1, kb);
    RAW_BAR();
    __builtin_amdgcn_s_setprio(1);
    #pragma unroll
    for (int j = 0; j < 4; ++j) {
      acc[0][j] = MFMA_BF16(ah0, bh[j], acc[0][j], 0, 0, 0);
      acc[0][j] = MFMA_BF16(ah0, bl[j], acc[0][j], 0, 0, 0);
      acc[0][j] = MFMA_BF16(al0, bh[j], acc[0][j], 0, 0, 0);
      acc[1][j] = MFMA_BF16(ah1, bh[j], acc[1][j], 0, 0, 0);
      acc[1][j] = MFMA_BF16(ah1, bl[j], acc[1][j], 0, 0, 0);
      acc[1][j] = MFMA_BF16(al1, bh[j], acc[1][j], 0, 0, 0);
    }
    __builtin_amdgcn_s_setprio(0);
    RAW_BAR();

    // ---- phase 1: A rows i=2,3; 24 MFMA ----
    bf16x8 ah2 = *(const bf16x8*)(&AsH[cur][rA[2]][sA[2]]);
    bf16x8 al2 = *(const bf16x8*)(&AsL[cur][rA[2]][sA[2]]);
    bf16x8 ah3 = *(const bf16x8*)(&AsH[cur][rA[3]][sA[3]]);
    bf16x8 al3 = *(const bf16x8*)(&AsL[cur][rA[3]][sA[3]]);
    if (pf) stage1(cur ^ 1, kb);
    RAW_BAR();
    __builtin_amdgcn_s_setprio(1);
    #pragma unroll
    for (int j = 0; j < 4; ++j) {
      acc[2][j] = MFMA_BF16(ah2, bh[j], acc[2][j], 0, 0, 0);
      acc[2][j] = MFMA_BF16(ah2, bl[j], acc[2][j], 0, 0, 0);
      acc[2][j] = MFMA_BF16(al2, bh[j], acc[2][j], 0, 0, 0);
      acc[3][j] = MFMA_BF16(ah3, bh[j], acc[3][j], 0, 0, 0);
      acc[3][j] = MFMA_BF16(ah3, bl[j], acc[3][j], 0, 0, 0);
      acc[3][j] = MFMA_BF16(al3, bh[j], acc[3][j], 0, 0, 0);
    }
    __builtin_amdgcn_s_setprio(0);
    VMCNT0();              // next buffer's 6 loads done
    RAW_BAR();             // all waves: next buffer ready, cur free
  }
}

__device__ __forceinline__ void single_core8(
    const short* __restrict__ A, const short* __restrict__ B,
    int lda, int ldb, int kIters, int blockM, int blockN,
    short (*As)[256][32], short (*Bs)[128][32], floatx4 (&acc)[4][4])
{
  const int tid  = threadIdx.x;
  const int lane = tid & 63;
  const int wave = tid >> 6;
  const int wm = (wave >> 1) * 64;
  const int wn = (wave & 1) * 64;
  const int fm = lane & 15;
  const int fu = lane >> 4;

  int rA[4], sA[4], rB[4], sB[4];
  #pragma unroll
  for (int i = 0; i < 4; ++i) {
    rA[i] = wm + i * 16 + fm;
    sA[i] = (fu ^ ((rA[i] >> 1) & 3)) * 8;
    rB[i] = wn + i * 16 + fm;
    sB[i] = (fu ^ ((rB[i] >> 1) & 3)) * 8;
  }

  floatx4 zero = {0.f, 0.f, 0.f, 0.f};
  #pragma unroll
  for (int i = 0; i < 4; ++i)
    #pragma unroll
    for (int j = 0; j < 4; ++j)
      acc[i][j] = zero;

  const int r0 = tid >> 2;
  const int u0 = tid & 3;
  const int su = (u0 ^ ((r0 >> 1) & 3)) * 8;
  const size_t a0 = (size_t)(blockM + r0) * lda + su;
  const size_t a1 = a0 + (size_t)128 * lda;
  const size_t b0 = (size_t)(blockN + r0) * ldb + su;

  auto stage0 = [&](int bf, int kb) {
    async_copy16(A + a0 + kb, &As[bf][r0][u0 * 8]);
    async_copy16(B + b0 + kb, &Bs[bf][r0][u0 * 8]);
  };
  auto stage1 = [&](int bf, int kb) {
    async_copy16(A + a1 + kb, &As[bf][r0 + 128][u0 * 8]);
  };

  stage0(0, 0);
  stage1(0, 0);
  VMCNT0();
  RAW_BAR();

  for (int kt = 0; kt < kIters; ++kt) {
    const int cur = kt & 1;
    const int kb = (kt + 1) * 32;
    const bool pf = (kt + 1) < kIters;

    bf16x8 bfr[4];
    #pragma unroll
    for (int j = 0; j < 4; ++j)
      bfr[j] = *(const bf16x8*)(&Bs[cur][rB[j]][sB[j]]);
    bf16x8 a0f = *(const bf16x8*)(&As[cur][rA[0]][sA[0]]);
    bf16x8 a1f = *(const bf16x8*)(&As[cur][rA[1]][sA[1]]);
    if (pf) stage0(cur ^ 1, kb);
    RAW_BAR();
    __builtin_amdgcn_s_setprio(1);
    #pragma unroll
    for (int j = 0; j < 4; ++j) {
      acc[0][j] = MFMA_BF16(a0f, bfr[j], acc[0][j], 0, 0, 0);
      acc[1][j] = MFMA_BF16(a1f, bfr[j], acc[1][j], 0, 0, 0);
    }
    __builtin_amdgcn_s_setprio(0);
    RAW_BAR();

    bf16x8 a2f = *(const bf16x8*)(&As[cur][rA[2]][sA[2]]);
    bf16x8 a3f = *(const bf16x8*)(&As[cur][rA[3]][sA[3]]);
    if (pf) stage1(cur ^ 1, kb);
    RAW_BAR();
    __builtin_amdgcn_s_setprio(1);
    #pragma unroll
    for (int j = 0; j < 4; ++j) {
      acc[2][j] = MFMA_BF16(a2f, bfr[j], acc[2][j], 0, 0, 0);
      acc[3][j] = MFMA_BF16(a3f, bfr[j], acc[3][j], 0, 0, 0);
    }
    __builtin_amdgcn_s_setprio(0);
    VMCNT0();
    RAW_BAR();
  }
}

// ---------------- W conversions ----------------
// [0,512): Wq split. [512,1024): Wk split. [1024,2048): Wv transpose (hi only);
// block 1024 also zeroes muSum + the sv8 work-queue counter.

__global__ __launch_bounds__(256) void k_cvt_w(
    const float* __restrict__ wq, const float* __restrict__ wk,
    const float* __restrict__ wv,
    short* __restrict__ wqh, short* __restrict__ wql,
    short* __restrict__ wkh, short* __restrict__ wkl,
    short* __restrict__ wvt, float* __restrict__ muSum,
    int* __restrict__ cnt)
{
  const int bid = blockIdx.x;
  const int tid = threadIdx.x;
  if (bid < 1024) {
    const float4* src;
    short *dh, *dl;
    size_t idx;
    if (bid < 512) {
      idx = (size_t)bid * 256 + tid;
      src = (const float4*)wq; dh = wqh; dl = wql;
    } else {
      idx = (size_t)(bid - 512) * 256 + tid;
      src = (const float4*)wk; dh = wkh; dl = wkl;
    }
    const float4 u4 = src[idx * 2];
    const float4 w4 = src[idx * 2 + 1];
    float f[8] = {u4.x, u4.y, u4.z, u4.w, w4.x, w4.y, w4.z, w4.w};
    short8v oh, ol;
    #pragma unroll
    for (int e = 0; e < 8; ++e) {
      const unsigned short h = f2bf(f[e]);
      oh[e] = (short)h;
      ol[e] = (short)f2bf(f[e] - bf2f(h));
    }
    *(short8v*)(dh + idx * 8) = oh;
    *(short8v*)(dl + idx * 8) = ol;
  } else {
    if (bid == 1024) {   // zero muSum + work queue before later kernels
      float4 z = {0.f, 0.f, 0.f, 0.f};
      ((float4*)muSum)[tid] = z;
      if (tid == 0) *cnt = 0;
    }
    const int rem = bid - 1024;
    const int bx = rem & 31, by = rem >> 5;
    const int tx = tid & 31, ty = tid >> 5;  // 32 x 8
    __shared__ float tile[32][33];
    const int colIn = bx * 32 + tx;
    #pragma unroll
    for (int i = 0; i < 4; ++i) {
      const int rowIn = by * 32 + ty + i * 8;
      tile[ty + i * 8][tx] = wv[(size_t)rowIn * D_DIM + colIn];
    }
    __syncthreads();
    const int colOut = by * 32 + tx;   // d (input row of Wv)
    #pragma unroll
    for (int i = 0; i < 4; ++i) {
      const int rowOut = bx * 32 + ty + i * 8;  // n (output col of Wv)
      wvt[(size_t)rowOut * D_DIM + colOut] = (short)f2bf(tile[tx][ty + i * 8]);
    }
  }
}

// ---------------- M^T GEMM (256 64x64 tiles, BK=64) + x split (4096), fused ----------------

__global__ __launch_bounds__(256) void k_m_cvtx(
    const short* __restrict__ wqh, const short* __restrict__ wql,
    const short* __restrict__ wkh, const short* __restrict__ wkl,
    short* __restrict__ mth, short* __restrict__ mtl,
    float* __restrict__ muSum,
    const float4* __restrict__ x,
    short* __restrict__ xh, short* __restrict__ xl)
{
  __shared__ alignas(16) short AsH[2][64][32];
  __shared__ alignas(16) short AsL[2][64][32];
  __shared__ alignas(16) short BsH[2][64][32];
  __shared__ alignas(16) short BsL[2][64][32];
  const int g = blockIdx.x;
  const int tid = threadIdx.x;

  if (g < 256) {
    // --- 64x64 M^T tile: A = Wk rows (e), B = Wq rows (d), inner = i ---
    floatx4 acc[2][2];
    const int blockM = (g >> 4) * 64;    // e
    const int blockN = (g & 15) * 64;    // d
    const int lane = tid & 63, wave = tid >> 6;
    const int wm = (wave >> 1) * 32, wn = (wave & 1) * 32;
    const int fm = lane & 15, fk = (lane >> 4) * 8;

    floatx4 zero = {0.f, 0.f, 0.f, 0.f};
    #pragma unroll
    for (int i = 0; i < 2; ++i)
      #pragma unroll
      for (int j = 0; j < 2; ++j)
        acc[i][j] = zero;

    const int sr = tid >> 2;             // row 0..63
    const int sc = (tid & 3) * 8;        // col 0..31 step 8
    const short* ah0 = wkh + (size_t)(blockM + sr) * D_DIM + sc;
    const short* al0 = wkl + (size_t)(blockM + sr) * D_DIM + sc;
    const short* bh0 = wqh + (size_t)(blockN + sr) * D_DIM + sc;
    const short* bl0 = wql + (size_t)(blockN + sr) * D_DIM + sc;
    short* ahB = &AsH[0][0][0]; short* alB = &AsL[0][0][0];
    short* bhB = &BsH[0][0][0]; short* blB = &BsL[0][0][0];
    const int l0 = tid * 8, l1 = (tid + 256) * 8;

    for (int kt = 0; kt < 16; ++kt) {    // BK=64
      const int kb = kt * 64;
      async_copy16(ah0 + kb, ahB + l0);
      async_copy16(ah0 + kb + 32, ahB + l1);
      async_copy16(al0 + kb, alB + l0);
      async_copy16(al0 + kb + 32, alB + l1);
      async_copy16(bh0 + kb, bhB + l0);
      async_copy16(bh0 + kb + 32, bhB + l1);
      async_copy16(bl0 + kb, blB + l0);
      async_copy16(bl0 + kb + 32, blB + l1);
      __syncthreads();
      #pragma unroll
      for (int ks = 0; ks < 2; ++ks) {
        bf16x8 ah[2], al[2], bh[2], bl[2];
        #pragma unroll
        for (int i = 0; i < 2; ++i) {
          ah[i] = *(const bf16x8*)(&AsH[ks][wm + i * 16 + fm][fk]);
          al[i] = *(const bf16x8*)(&AsL[ks][wm + i * 16 + fm][fk]);
        }
        #pragma unroll
        for (int j = 0; j < 2; ++j) {
          bh[j] = *(const bf16x8*)(&BsH[ks][wn + j * 16 + fm][fk]);
          bl[j] = *(const bf16x8*)(&BsL[ks][wn + j * 16 + fm][fk]);
        }
        #pragma unroll
        for (int i = 0; i < 2; ++i)
          #pragma unroll
          for (int j = 0; j < 2; ++j) {
            acc[i][j] = MFMA_BF16(ah[i], bh[j], acc[i][j], 0, 0, 0);
            acc[i][j] = MFMA_BF16(ah[i], bl[j], acc[i][j], 0, 0, 0);
            acc[i][j] = MFMA_BF16(al[i], bh[j], acc[i][j], 0, 0, 0);
          }
      }
      __syncthreads();
    }

    const int rb = wm + ((lane >> 4) << 2);
    const int cb = wn + (lane & 15);
    #pragma unroll
    for (int i = 0; i < 2; ++i)
      #pragma unroll
      for (int j = 0; j < 2; ++j) {
        const int n = blockN + cb + j * 16;
        #pragma unroll
        for (int r = 0; r < 2 * 2; ++r) {
          const int m = blockM + rb + i * 16 + r;
          const float f = acc[i][j][r];
          const unsigned short h = f2bf(f);
          mth[(size_t)m * D_DIM + n] = (short)h;
          mtl[(size_t)m * D_DIM + n] = (short)f2bf(f - bf2f(h));
        }
      }
    // mu partials: per row e, sum over this block's 64 d-cols
    #pragma unroll
    for (int i = 0; i < 2; ++i)
      #pragma unroll
      for (int r = 0; r < 4; ++r) {
        float v = acc[i][0][r] + acc[i][1][r];
        v += __shfl_xor(v, 1); v += __shfl_xor(v, 2);
        v += __shfl_xor(v, 4); v += __shfl_xor(v, 8);
        if ((lane & 15) == 0)
          atomicAdd(&muSum[blockM + rb + i * 16 + r], v);
      }
  } else {
    const size_t idx = (size_t)(g - 256) * 256 + tid;
    const float4 u4 = x[idx * 2];
    const float4 w4 = x[idx * 2 + 1];
    float f[8] = {u4.x, u4.y, u4.z, u4.w, w4.x, w4.y, w4.z, w4.w};
    short8v oh, ol;
    #pragma unroll
    for (int e = 0; e < 8; ++e) {
      const unsigned short h = f2bf(f[e]);
      oh[e] = (short)h;
      ol[e] = (short)f2bf(f[e] - bf2f(h));
    }
    *(short8v*)(xh + idx * 8) = oh;
    *(short8v*)(xl + idx * 8) = ol;
  }
}

// ---------------- per-row stats over reconstructed split-x ----------------

__global__ __launch_bounds__(256) void k_rowstats(
    const short* __restrict__ xh, const short* __restrict__ xl,
    const float* __restrict__ muSum, float* __restrict__ sq, float* __restrict__ u)
{
  const int r = blockIdx.x, tid = threadIdx.x;
  const ushort4 h = *(const ushort4*)(xh + (size_t)r * D_DIM + tid * 4);
  const ushort4 l = *(const ushort4*)(xl + (size_t)r * D_DIM + tid * 4);
  const float4 m4 = *(const float4*)(muSum + tid * 4);
  const float x0 = bf2f(h.x) + bf2f(l.x);
  const float x1 = bf2f(h.y) + bf2f(l.y);
  const float x2 = bf2f(h.z) + bf2f(l.z);
  const float x3 = bf2f(h.w) + bf2f(l.w);
  float s = x0 + x1 + x2 + x3;
  float uu = m4.x * x0 + m4.y * x1 + m4.z * x2 + m4.w * x3;
  #pragma unroll
  for (int off = 32; off > 0; off >>= 1) {
    s  += __shfl_xor(s, off);
    uu += __shfl_xor(uu, off);
  }
  __shared__ float ps[4], pu[4];
  if ((tid & 63) == 0) { ps[tid >> 6] = s; pu[tid >> 6] = uu; }
  __syncthreads();
  if (tid == 0) {
    sq[r] = ps[0] + ps[1] + ps[2] + ps[3];
    u[r]  = (pu[0] + pu[1] + pu[2] + pu[3]) * (1.0f / 1024.0f);
  }
}

// ---------------- N~ = x M - sq mu^T, 256x128 tiles, dbuf phased core ----------------
// 256 blocks = exactly 1 block/CU machine fill.

__global__ __launch_bounds__(512) void k_gemm_n8(
    const short* __restrict__ xh, const short* __restrict__ xl,
    const short* __restrict__ mth, const short* __restrict__ mtl,
    const float* __restrict__ sq, const float* __restrict__ muSum,
    short* __restrict__ nh, short* __restrict__ nl)
{
  __shared__ alignas(16) short AsH[2][256][32];
  __shared__ alignas(16) short AsL[2][256][32];
  __shared__ alignas(16) short BsH[2][128][32];
  __shared__ alignas(16) short BsL[2][128][32];
  floatx4 acc[4][4];
  const int g = blockIdx.x;
  const int swz = (g & 7) * 32 + (g >> 3);     // XCD-contiguous chunks
  const int blockM = (swz >> 3) * 256;         // global row (b,s)
  const int blockN = (swz & 7) * 128;          // e
  split_core8(xh, xl, mth, mtl, D_DIM, D_DIM, D_DIM / 32,
              blockM, blockN, AsH, AsL, BsH, BsL, acc);

  const int tid = threadIdx.x, lane = tid & 63, wave = tid >> 6;
  const int wm = (wave >> 1) * 64, wn = (wave & 1) * 64;
  const int rb = wm + ((lane >> 4) << 2);
  const int cb = wn + (lane & 15);
  #pragma unroll
  for (int i = 0; i < 4; ++i)
    #pragma unroll
    for (int j = 0; j < 4; ++j) {
      const int n = blockN + cb + j * 16;
      const float muv = muSum[n] * (1.0f / 1024.0f);
      #pragma unroll
      for (int r = 0; r < 4; ++r) {
        const int m = blockM + rb + i * 16 + r;
        const float f = acc[i][j][r] - sq[m] * muv;   // deflate
        const unsigned short h = f2bf(f);
        nh[(size_t)m * D_DIM + n] = (short)h;
        nl[(size_t)m * D_DIM + n] = (short)f2bf(f - bf2f(h));
      }
    }
}

// ---------------- fused scores + V, persistent 256-block work queue ----------------
// items 0..287: score tiles (256x128, lower-tri, heavy — drained first)
// items 288..543: V tiles (256x128, light — tail fillers)

__global__ __launch_bounds__(512) void k_gemm_sv8(
    const short* __restrict__ nh, const short* __restrict__ nl,
    const short* __restrict__ xh, const short* __restrict__ xl,
    const float* __restrict__ sq, const float* __restrict__ u,
    const short* __restrict__ wvt, float* __restrict__ attn,
    short* __restrict__ vt, int* __restrict__ cnt)
{
  __shared__ alignas(16) short AsH[2][256][32];
  __shared__ alignas(16) short AsL[2][256][32];
  __shared__ alignas(16) short BsH[2][128][32];
  __shared__ alignas(16) short BsL[2][128][32];
  __shared__ int s_item;

  const int tid = threadIdx.x, lane = tid & 63, wave = tid >> 6;
  const int wm = (wave >> 1) * 64, wn = (wave & 1) * 64;
  const int rb = wm + ((lane >> 4) << 2);
  const int cb = wn + (lane & 15);

  for (;;) {
    if (tid == 0) s_item = atomicAdd(cnt, 1);
    __syncthreads();
    const int item = s_item;
    if (item >= 544) return;     // block-uniform exit

    floatx4 acc[4][4];
    if (item < 288) {
      // scores: per batch, lower-tri tiles of 256 rows x 128 cols:
      // bi in [0,8), bj in [0, 2*bi+2). 72/batch.
      const int b = item / 72;
      int t = item - b * 72;
      int bi = 0;
      while (t >= 2 * bi + 2) { t -= 2 * bi + 2; ++bi; }
      const int bj = t;

      const size_t boff = (size_t)b * S_LEN * D_DIM;
      split_core8(nh + boff, nl + boff, xh + boff, xl + boff,
                  D_DIM, D_DIM, D_DIM / 32, bi * 256, bj * 128,
                  AsH, AsL, BsH, BsL, acc);

      float* out = attn + (size_t)b * S_LEN * S_LEN;
      const int rowBase = (b << 11) + bi * 256;
      const int colBase = (b << 11) + bj * 128;
      #pragma unroll
      for (int j = 0; j < 4; ++j) {
        const int n = bj * 128 + cb + j * 16;
        const float uv = u[colBase + cb + j * 16];
        #pragma unroll
        for (int i = 0; i < 4; ++i)
          #pragma unroll
          for (int r = 0; r < 4; ++r) {
            const int m = bi * 256 + rb + i * 16 + r;
            const float sv = sq[rowBase + rb + i * 16 + r];
            out[(size_t)m * S_LEN + n] = acc[i][j][r] + sv * uv;  // raw
          }
      }
    } else {
      const int vb = item - 288;            // 0..255
      const int blockM = (vb >> 3) * 256;   // global row over 8192
      const int blockN = (vb & 7) * 128;    // d
      single_core8(xh, wvt, D_DIM, D_DIM, D_DIM / 32, blockM, blockN,
                   AsH, BsH, acc);
      #pragma unroll
      for (int i = 0; i < 4; ++i)
        #pragma unroll
        for (int j = 0; j < 4; ++j) {
          const int n = blockN + cb + j * 16;   // d index
          const int m0 = blockM + rb + i * 16;  // global row, 4-aligned
          const int b = m0 >> 11;
          const int s0 = m0 & (S_LEN - 1);
          ushort4 pk;
          pk.x = f2bf(acc[i][j][0]); pk.y = f2bf(acc[i][j][1]);
          pk.z = f2bf(acc[i][j][2]); pk.w = f2bf(acc[i][j][3]);
          *(ushort4*)(vt + ((size_t)b * D_DIM + n) * S_LEN + s0) = pk;
        }
    }
  }
}

// ---------------- softmax: prefix-only reads, band-limited pb writes ----------------

__global__ __launch_bounds__(256) void k_softmax(float* __restrict__ attn,
                                                 short* __restrict__ pb) {
  const int b = blockIdx.x >> 11;
  const int q = blockIdx.x & (S_LEN - 1);
  float* row  = attn + ((size_t)b * S_LEN + q) * S_LEN;
  short* prow = pb   + ((size_t)b * S_LEN + q) * S_LEN;
  const int tid = threadIdx.x;
  const int k0 = tid * 8;
  const int kBand = ((q >> 7) + 1) << 7;   // 128-aligned band end
  __shared__ float sMax[4], sSum[4];

  float v[8];
  if (k0 <= q) {               // load only the live prefix
    const float4 a0 = *(const float4*)(row + k0);
    const float4 a1 = *(const float4*)(row + k0 + 4);
    v[0] = a0.x; v[1] = a0.y; v[2] = a0.z; v[3] = a0.w;
    v[4] = a1.x; v[5] = a1.y; v[6] = a1.z; v[7] = a1.w;
  } else {
    #pragma unroll
    for (int e = 0; e < 8; ++e) v[e] = -3.0e38f;
  }

  float mx = -3.0e38f;
  #pragma unroll
  for (int e = 0; e < 8; ++e) {
    v[e] = (k0 + e <= q) ? v[e] : -3.0e38f;
    mx = fmaxf(mx, v[e]);
  }
  #pragma unroll
  for (int off = 32; off > 0; off >>= 1) mx = fmaxf(mx, __shfl_xor(mx, off));
  if ((tid & 63) == 0) sMax[tid >> 6] = mx;
  __syncthreads();
  mx = fmaxf(fmaxf(sMax[0], sMax[1]), fmaxf(sMax[2], sMax[3]));

  float s = 0.f;
  #pragma unroll
  for (int e = 0; e < 8; ++e) {
    const float p = (k0 + e <= q) ? __expf((v[e] - mx) * 0.03125f) : 0.f;
    v[e] = p;
    s += p;
  }
  #pragma unroll
  for (int off = 32; off > 0; off >>= 1) s += __shfl_xor(s, off);
  if ((tid & 63) == 0) sSum[tid >> 6] = s;
  __syncthreads();
  s = sSum[0] + sSum[1] + sSum[2] + sSum[3];
  const float inv = 1.0f / s;

  float o[8];
  #pragma unroll
  for (int e = 0; e < 8; ++e) o[e] = v[e] * inv;   // 0 for masked
  float4 w0 = {o[0], o[1], o[2], o[3]};
  float4 w1 = {o[4], o[5], o[6], o[7]};
  *(float4*)(row + k0) = w0;
  *(float4*)(row + k0 + 4) = w1;
  if (k0 < kBand) {
    ushort4 p0, p1;
    p0.x = f2bf(o[0]); p0.y = f2bf(o[1]); p0.z = f2bf(o[2]); p0.w = f2bf(o[3]);
    p1.x = f2bf(o[4]); p1.y = f2bf(o[5]); p1.z = f2bf(o[6]); p1.w = f2bf(o[7]);
    *(ushort4*)(prow + k0) = p0;
    *(ushort4*)(prow + k0 + 4) = p1;
  }
}

// ---------------- context = P @ V, 128^2, BK=64 k-plane LDS, swizzled ----------------
// T2 swizzle (rule 21, both-sides): source col unit pre-swizzled
// su = (u0 ^ ((r0>>1)&3))*8 with linear gload_lds dest; frag reads use
// the same XOR. Old unswizzled reads were an 8-way bank conflict.

__global__ __launch_bounds__(256) void k_gemm_ctx(
    const short* __restrict__ pb, const short* __restrict__ vt,
    float* __restrict__ ctx)
{
  __shared__ alignas(16) short As2[2][128][32];
  __shared__ alignas(16) short Bs2[2][128][32];
  floatx4 acc[4][4];
  const int b = blockIdx.z;
  const int by = 15 - blockIdx.y;        // heavy K-loops dispatched first
  const int blockM = by * 128;           // q
  const int blockN = blockIdx.x * 128;   // d
  const int kIters = (by + 1) * 2;       // BK=64; k <= blockM+127 only
  const short* A = pb + (size_t)b * S_LEN * S_LEN;
  const short* B = vt + (size_t)b * D_DIM * S_LEN;

  const int tid = threadIdx.x, lane = tid & 63, wave = tid >> 6;
  const int wm = (wave >> 1) * 64, wn = (wave & 1) * 64;
  const int fm = lane & 15;
  const int fu = lane >> 4;

  int rA[4], sA[4], rB[4], sB[4];
  #pragma unroll
  for (int i = 0; i < 4; ++i) {
    rA[i] = wm + i * 16 + fm;
    sA[i] = (fu ^ ((rA[i] >> 1) & 3)) * 8;
    rB[i] = wn + i * 16 + fm;
    sB[i] = (fu ^ ((rB[i] >> 1) & 3)) * 8;
  }

  floatx4 zero = {0.f, 0.f, 0.f, 0.f};
  #pragma unroll
  for (int i = 0; i < 4; ++i)
    #pragma unroll
    for (int j = 0; j < 4; ++j)
      acc[i][j] = zero;

  const int r0 = tid >> 2;               // 0..63
  const int u0 = tid & 3;
  const int su = (u0 ^ ((r0 >> 1) & 3)) * 8;   // pre-swizzled source unit
  // rows r0 and r0+64 share ((row>>1)&3) (64/2 = 32, 32%4 == 0) -> same su
  const short* a0 = A + (size_t)(blockM + r0) * S_LEN + su;
  const short* a1 = a0 + (size_t)64 * S_LEN;
  const short* b0 = B + (size_t)(blockN + r0) * S_LEN + su;
  const short* b1 = b0 + (size_t)64 * S_LEN;
  short* asBase = &As2[0][0][0];
  short* bsBase = &Bs2[0][0][0];
  short* as0 = asBase + (size_t)tid * 8;             // [0][r0][u0*8]
  short* as1 = asBase + (size_t)(tid + 256) * 8;     // [0][r0+64][u0*8]
  short* as2 = asBase + (size_t)(tid + 512) * 8;     // [1][r0][u0*8]
  short* as3 = asBase + (size_t)(tid + 768) * 8;     // [1][r0+64][u0*8]
  short* bs0 = bsBase + (size_t)tid * 8;
  short* bs1 = bsBase + (size_t)(tid + 256) * 8;
  short* bs2 = bsBase + (size_t)(tid + 512) * 8;
  short* bs3 = bsBase + (size_t)(tid + 768) * 8;

  for (int kt = 0; kt < kIters; ++kt) {
    const int kb = kt * 64;
    async_copy16(a0 + kb, as0);
    async_copy16(a1 + kb, as1);
    async_copy16(a0 + kb + 32, as2);
    async_copy16(a1 + kb + 32, as3);
    async_copy16(b0 + kb, bs0);
    async_copy16(b1 + kb, bs1);
    async_copy16(b0 + kb + 32, bs2);
    async_copy16(b1 + kb + 32, bs3);
    __syncthreads();
    #pragma unroll
    for (int ks = 0; ks < 2; ++ks) {
      bf16x8 af[4], bfr[4];
      #pragma unroll
      for (int i = 0; i < 4; ++i)
        af[i] = *(const bf16x8*)(&As2[ks][rA[i]][sA[i]]);
      #pragma unroll
      for (int j = 0; j < 4; ++j)
        bfr[j] = *(const bf16x8*)(&Bs2[ks][rB[j]][sB[j]]);
      __builtin_amdgcn_s_setprio(1);
      #pragma unroll
      for (int i = 0; i < 4; ++i)
        #pragma unroll
        for (int j = 0; j < 4; ++j)
          acc[i][j] = MFMA_BF16(af[i], bfr[j], acc[i][j], 0, 0, 0);
      __builtin_amdgcn_s_setprio(0);
    }
    __syncthreads();
  }

  float* out = ctx + (size_t)b * S_LEN * D_DIM;
  const int rb = wm + ((lane >> 4) << 2);
  const int cb = wn + (lane & 15);
  #pragma unroll
  for (int i = 0; i < 4; ++i)
    #pragma unroll
    for (int j = 0; j < 4; ++j) {
      const int n = blockN + cb + j * 16;
      #pragma unroll
      for (int r = 0; r < 4; ++r) {
        const int m = blockM + rb + i * 16 + r;
        out[(size_t)m * D_DIM + n] = acc[i][j][r];
      }
    }
}

// ---------------- launch ----------------

extern "C" void kernel_launch(void* const* d_in, const int* in_sizes, int n_in,
                              void* d_out, int out_size, void* d_ws, size_t ws_size,
                              hipStream_t stream) {
  const float* x  = (const float*)d_in[0];
  const float* wq = (const float*)d_in[1];
  const float* wk = (const float*)d_in[2];
  const float* wv = (const float*)d_in[3];

  float* out  = (float*)d_out;
  float* ctx  = out;                                       // [4,2048,1024]
  float* attn = out + (size_t)NBATCH * S_LEN * D_DIM;      // [4,2048,2048]

  // workspace (shorts), ~94 MiB; pb aliases nh/nl (dead after scores GEMM)
  short* ws  = (short*)d_ws;
  short* xh  = ws;                                  // 8M
  short* xl  = xh + (size_t)8 * MEG;                // 8M
  short* wqh = xl + (size_t)8 * MEG;                // 1M Wq hi (original layout)
  short* wql = wqh + (size_t)1 * MEG;               // 1M Wq lo
  short* wkh = wql + (size_t)1 * MEG;               // 1M Wk hi
  short* wkl = wkh + (size_t)1 * MEG;               // 1M Wk lo
  short* wvt = wkl + (size_t)1 * MEG;               // 1M Wv^T hi
  short* mth = wvt + (size_t)1 * MEG;               // 1M M^T hi
  short* mtl = mth + (size_t)1 * MEG;               // 1M M^T lo
  short* nh  = mtl + (size_t)1 * MEG;               // 8M N~ hi
  short* nl  = nh + (size_t)8 * MEG;                // 8M N~ lo
  short* vt  = nl + (size_t)8 * MEG;                // 8M V^T [b,d,s]
  short* pb  = nh;                                  // 16M alias (nh+nl)
  float* fb  = (float*)(vt + (size_t)8 * MEG);
  float* muS = fb;                                  // 1024 (sum over d, not mean)
  float* sq  = fb + 1024;                           // 8192
  float* u   = sq + 8192;                           // 8192
  int*   cnt = (int*)(u + 8192);                    // sv8 work-queue counter

  k_cvt_w<<<2048, 256, 0, stream>>>(wq, wk, wv, wqh, wql, wkh, wkl, wvt,
                                    muS, cnt);
  k_m_cvtx<<<4352, 256, 0, stream>>>(wqh, wql, wkh, wkl, mth, mtl, muS,
                                     (const float4*)x, xh, xl);
  k_rowstats<<<8192, 256, 0, stream>>>(xh, xl, muS, sq, u);
  k_gemm_n8<<<256, 512, 0, stream>>>(xh, xl, mth, mtl, sq, muS, nh, nl);
  k_gemm_sv8<<<256, 512, 0, stream>>>(nh, nl, xh, xl, sq, u, wvt, attn,
                                      vt, cnt);
  k_softmax<<<NBATCH * S_LEN, 256, 0, stream>>>(attn, pb);
  k_gemm_ctx<<<dim3(8, 16, 4), 256, 0, stream>>>(pb, vt, ctx);
}

// Round 15
// 353.514 us; speedup vs baseline: 1.0381x; 1.0007x over previous
//
#include <hip/hip_runtime.h>
#include <cstdint>
#include <cstddef>

// CausalAttention B=4 S=2048 D=1024.
// d_out = [context (4*2048*1024 f32)] ++ [attn_scores (4*2048*2048 f32)]
//
// scores = x M x^T, M[d,e] = sum_i Wq[d,i] Wk[e,i]:
//   M^T = bt(A=Wk, B=Wq)   (split bf16 3-pass; mu fused via atomics)
//   N~  = x M - sq*mu^T    (split; mean-deflated)
//   S   = N~ x^T + sq*u    (split, lower-tri; exact f32 rank-1 add-back)
// Round-25: r14 FAILED (absmax 2.2e6) — score tiles write RAW scores
// into the dead zone (first 128 rows of each 256-row tile x bj=2bi+1
// col tile), which raced with the V-item zero-fill inside the same
// persistent kernel. Fix: band-guard the score epilogue store
// ((n>>7) <= (m>>7)) so the dead zone is single-writer (V zero-fill
// only); keep band-limited softmax (64->~33MB f32 writes) + zero-fill.
// Base is r13-exact (353.75us best).

#define S_LEN 2048
#define D_DIM 1024
#define NBATCH 4
#define MEG (1024 * 1024)

typedef __attribute__((ext_vector_type(4))) float floatx4;
typedef __attribute__((ext_vector_type(8))) __bf16 bf16x8;
typedef __attribute__((ext_vector_type(8))) short short8v;

__device__ __forceinline__ unsigned short f2bf(float f) {
  union { float f; unsigned u; } v; v.f = f;
  unsigned r = v.u + 0x7FFF + ((v.u >> 16) & 1);   // round-to-nearest-even
  return (unsigned short)(r >> 16);
}
__device__ __forceinline__ float bf2f(unsigned short h) {
  union { unsigned u; float f; } v; v.u = ((unsigned)h) << 16; return v.f;
}

__device__ __forceinline__ void async_copy16(const void* g, void* l) {
  __builtin_amdgcn_global_load_lds(
      (const __attribute__((address_space(1))) void*)g,
      (__attribute__((address_space(3))) void*)l, 16, 0, 0);
}

#define VMCNT0() asm volatile("s_waitcnt vmcnt(0)" ::: "memory")
#define RAW_BAR() __builtin_amdgcn_s_barrier()
#define MFMA_BF16 __builtin_amdgcn_mfma_f32_16x16x32_bf16

// ============ 512-thread, 256x128-tile phased cores (BK=32, dbuf) ============
// 8 waves as 4(M)x2(N); per-wave 64x64 (4x4 frags of 16x16).
// LDS swizzle (verified, conflicts=0): LDS[row][v] holds
// global[row][v ^ ((row>>1)&3)] (16B units); staged via pre-swizzled global
// source (dest linear for global_load_lds), read back with the same XOR.
// 2-phase schedule — best measured (105us sv8, 29% MfmaUtil).

__device__ __forceinline__ void split_core8(
    const short* __restrict__ Ah, const short* __restrict__ Al,
    const short* __restrict__ Bh, const short* __restrict__ Bl,
    int lda, int ldb, int kIters, int blockM, int blockN,
    short (*AsH)[256][32], short (*AsL)[256][32],
    short (*BsH)[128][32], short (*BsL)[128][32],
    floatx4 (&acc)[4][4])
{
  const int tid  = threadIdx.x;          // 0..511
  const int lane = tid & 63;
  const int wave = tid >> 6;             // 0..7
  const int wm = (wave >> 1) * 64;       // 0,64,128,192
  const int wn = (wave & 1) * 64;        // 0,64
  const int fm = lane & 15;
  const int fu = lane >> 4;              // 16B unit 0..3

  int rA[4], sA[4], rB[4], sB[4];
  #pragma unroll
  for (int i = 0; i < 4; ++i) {
    rA[i] = wm + i * 16 + fm;
    sA[i] = (fu ^ ((rA[i] >> 1) & 3)) * 8;
    rB[i] = wn + i * 16 + fm;
    sB[i] = (fu ^ ((rB[i] >> 1) & 3)) * 8;
  }

  floatx4 zero = {0.f, 0.f, 0.f, 0.f};
  #pragma unroll
  for (int i = 0; i < 4; ++i)
    #pragma unroll
    for (int j = 0; j < 4; ++j)
      acc[i][j] = zero;

  const int r0 = tid >> 2;               // 0..127
  const int u0 = tid & 3;
  const int su = (u0 ^ ((r0 >> 1) & 3)) * 8;   // pre-swizzled source unit
  const size_t a0 = (size_t)(blockM + r0) * lda + su;
  const size_t a1 = a0 + (size_t)128 * lda;
  const size_t b0 = (size_t)(blockN + r0) * ldb + su;

  auto stage0 = [&](int bf, int kb) {
    async_copy16(Ah + a0 + kb, &AsH[bf][r0][u0 * 8]);
    async_copy16(Al + a0 + kb, &AsL[bf][r0][u0 * 8]);
    async_copy16(Bh + b0 + kb, &BsH[bf][r0][u0 * 8]);
  };
  auto stage1 = [&](int bf, int kb) {
    async_copy16(Ah + a1 + kb, &AsH[bf][r0 + 128][u0 * 8]);
    async_copy16(Al + a1 + kb, &AsL[bf][r0 + 128][u0 * 8]);
    async_copy16(Bl + b0 + kb, &BsL[bf][r0][u0 * 8]);
  };

  stage0(0, 0);
  stage1(0, 0);
  VMCNT0();
  RAW_BAR();

  for (int kt = 0; kt < kIters; ++kt) {
    const int cur = kt & 1;
    const int kb = (kt + 1) * 32;
    const bool pf = (kt + 1) < kIters;

    // ---- phase 0: B frags + A rows i=0,1; 24 MFMA ----
    bf16x8 bh[4], bl[4];
    #pragma unroll
    for (int j = 0; j < 4; ++j) {
      bh[j] = *(const bf16x8*)(&BsH[cur][rB[j]][sB[j]]);
      bl[j] = *(const bf16x8*)(&BsL[cur][rB[j]][sB[j]]);
    }
    bf16x8 ah0 = *(const bf16x8*)(&AsH[cur][rA[0]][sA[0]]);
    bf16x8 al0 = *(const bf16x8*)(&AsL[cur][rA[0]][sA[0]]);
    bf16x8 ah1 = *(const bf16x8*)(&AsH[cur][rA[1]][sA[1]]);
    bf16x8 al1 = *(const bf16x8*)(&AsL[cur][rA[1]][sA[1]]);
    if (pf) stage0(cur ^ 1, kb);
    RAW_BAR();
    __builtin_amdgcn_s_setprio(1);
    #pragma unroll
    for (int j = 0; j < 4; ++j) {
      acc[0][j] = MFMA_BF16(ah0, bh[j], acc[0][j], 0, 0, 0);
      acc[0][j] = MFMA_BF16(ah0, bl[j], acc[0][j], 0, 0, 0);
      acc[0][j] = MFMA_BF16(al0, bh[j], acc[0][j], 0, 0, 0);
      acc[1][j] = MFMA_BF16(ah1, bh[j], acc[1][j], 0, 0, 0);
      acc[1][j] = MFMA_BF16(ah1, bl[j], acc[1][j], 0, 0, 0);
      acc[1][j] = MFMA_BF16(al1, bh[j], acc[1][j], 0, 0, 0);
    }
    __builtin_amdgcn_s_setprio(0);
    RAW_BAR();

    // ---- phase 1: A rows i=2,3; 24 MFMA ----
    bf16x8 ah2 = *(const bf16x8*)(&AsH[cur][rA[2]][sA[2]]);
    bf16x8 al2 = *(const bf16x8*)(&AsL[cur][rA[2]][sA[2]]);
    bf16x8 ah3 = *(const bf16x8*)(&AsH[cur][rA[3]][sA[3]]);
    bf16x8 al3 = *(const bf16x8*)(&AsL[cur][rA[3]][sA[3]]);
    if (pf) stage1(cur ^ 1, kb);
    RAW_BAR();
    __builtin_amdgcn_s_setprio(1);
    #pragma unroll
    for (int j = 0; j < 4; ++j) {
      acc[2][j] = MFMA_BF16(ah2, bh[j], acc[2][j], 0, 0, 0);
      acc[2][j] = MFMA_BF16(ah2, bl[j], acc[2][j], 0, 0, 0);
      acc[2][j] = MFMA_BF16(al2, bh[j], acc[2][j], 0, 0, 0);
      acc[3][j] = MFMA_BF16(ah3, bh[j], acc[3][j], 0, 0, 0);
      acc[3][j] = MFMA_BF16(ah3, bl[j], acc[3][j], 0, 0, 0);
      acc[3][j] = MFMA_BF16(al3, bh[j], acc[3][j], 0, 0, 0);
    }
    __builtin_amdgcn_s_setprio(0);
    VMCNT0();              // next buffer's 6 loads done
    RAW_BAR();             // all waves: next buffer ready, cur free
  }
}

__device__ __forceinline__ void single_core8(
    const short* __restrict__ A, const short* __restrict__ B,
    int lda, int ldb, int kIters, int blockM, int blockN,
    short (*As)[256][32], short (*Bs)[128][32], floatx4 (&acc)[4][4])
{
  const int tid  = threadIdx.x;
  const int lane = tid & 63;
  const int wave = tid >> 6;
  const int wm = (wave >> 1) * 64;
  const int wn = (wave & 1) * 64;
  const int fm = lane & 15;
  const int fu = lane >> 4;

  int rA[4], sA[4], rB[4], sB[4];
  #pragma unroll
  for (int i = 0; i < 4; ++i) {
    rA[i] = wm + i * 16 + fm;
    sA[i] = (fu ^ ((rA[i] >> 1) & 3)) * 8;
    rB[i] = wn + i * 16 + fm;
    sB[i] = (fu ^ ((rB[i] >> 1) & 3)) * 8;
  }

  floatx4 zero = {0.f, 0.f, 0.f, 0.f};
  #pragma unroll
  for (int i = 0; i < 4; ++i)
    #pragma unroll
    for (int j = 0; j < 4; ++j)
      acc[i][j] = zero;

  const int r0 = tid >> 2;
  const int u0 = tid & 3;
  const int su = (u0 ^ ((r0 >> 1) & 3)) * 8;
  const size_t a0 = (size_t)(blockM + r0) * lda + su;
  const size_t a1 = a0 + (size_t)128 * lda;
  const size_t b0 = (size_t)(blockN + r0) * ldb + su;

  auto stage0 = [&](int bf, int kb) {
    async_copy16(A + a0 + kb, &As[bf][r0][u0 * 8]);
    async_copy16(B + b0 + kb, &Bs[bf][r0][u0 * 8]);
  };
  auto stage1 = [&](int bf, int kb) {
    async_copy16(A + a1 + kb, &As[bf][r0 + 128][u0 * 8]);
  };

  stage0(0, 0);
  stage1(0, 0);
  VMCNT0();
  RAW_BAR();

  for (int kt = 0; kt < kIters; ++kt) {
    const int cur = kt & 1;
    const int kb = (kt + 1) * 32;
    const bool pf = (kt + 1) < kIters;

    bf16x8 bfr[4];
    #pragma unroll
    for (int j = 0; j < 4; ++j)
      bfr[j] = *(const bf16x8*)(&Bs[cur][rB[j]][sB[j]]);
    bf16x8 a0f = *(const bf16x8*)(&As[cur][rA[0]][sA[0]]);
    bf16x8 a1f = *(const bf16x8*)(&As[cur][rA[1]][sA[1]]);
    if (pf) stage0(cur ^ 1, kb);
    RAW_BAR();
    __builtin_amdgcn_s_setprio(1);
    #pragma unroll
    for (int j = 0; j < 4; ++j) {
      acc[0][j] = MFMA_BF16(a0f, bfr[j], acc[0][j], 0, 0, 0);
      acc[1][j] = MFMA_BF16(a1f, bfr[j], acc[1][j], 0, 0, 0);
    }
    __builtin_amdgcn_s_setprio(0);
    RAW_BAR();

    bf16x8 a2f = *(const bf16x8*)(&As[cur][rA[2]][sA[2]]);
    bf16x8 a3f = *(const bf16x8*)(&As[cur][rA[3]][sA[3]]);
    if (pf) stage1(cur ^ 1, kb);
    RAW_BAR();
    __builtin_amdgcn_s_setprio(1);
    #pragma unroll
    for (int j = 0; j < 4; ++j) {
      acc[2][j] = MFMA_BF16(a2f, bfr[j], acc[2][j], 0, 0, 0);
      acc[3][j] = MFMA_BF16(a3f, bfr[j], acc[3][j], 0, 0, 0);
    }
    __builtin_amdgcn_s_setprio(0);
    VMCNT0();
    RAW_BAR();
  }
}

// ---------------- W conversions ----------------
// [0,512): Wq split. [512,1024): Wk split. [1024,2048): Wv transpose (hi only);
// block 1024 also zeroes muSum + the sv8 work-queue counter.

__global__ __launch_bounds__(256) void k_cvt_w(
    const float* __restrict__ wq, const float* __restrict__ wk,
    const float* __restrict__ wv,
    short* __restrict__ wqh, short* __restrict__ wql,
    short* __restrict__ wkh, short* __restrict__ wkl,
    short* __restrict__ wvt, float* __restrict__ muSum,
    int* __restrict__ cnt)
{
  const int bid = blockIdx.x;
  const int tid = threadIdx.x;
  if (bid < 1024) {
    const float4* src;
    short *dh, *dl;
    size_t idx;
    if (bid < 512) {
      idx = (size_t)bid * 256 + tid;
      src = (const float4*)wq; dh = wqh; dl = wql;
    } else {
      idx = (size_t)(bid - 512) * 256 + tid;
      src = (const float4*)wk; dh = wkh; dl = wkl;
    }
    const float4 u4 = src[idx * 2];
    const float4 w4 = src[idx * 2 + 1];
    float f[8] = {u4.x, u4.y, u4.z, u4.w, w4.x, w4.y, w4.z, w4.w};
    short8v oh, ol;
    #pragma unroll
    for (int e = 0; e < 8; ++e) {
      const unsigned short h = f2bf(f[e]);
      oh[e] = (short)h;
      ol[e] = (short)f2bf(f[e] - bf2f(h));
    }
    *(short8v*)(dh + idx * 8) = oh;
    *(short8v*)(dl + idx * 8) = ol;
  } else {
    if (bid == 1024) {   // zero muSum + work queue before later kernels
      float4 z = {0.f, 0.f, 0.f, 0.f};
      ((float4*)muSum)[tid] = z;
      if (tid == 0) *cnt = 0;
    }
    const int rem = bid - 1024;
    const int bx = rem & 31, by = rem >> 5;
    const int tx = tid & 31, ty = tid >> 5;  // 32 x 8
    __shared__ float tile[32][33];
    const int colIn = bx * 32 + tx;
    #pragma unroll
    for (int i = 0; i < 4; ++i) {
      const int rowIn = by * 32 + ty + i * 8;
      tile[ty + i * 8][tx] = wv[(size_t)rowIn * D_DIM + colIn];
    }
    __syncthreads();
    const int colOut = by * 32 + tx;   // d (input row of Wv)
    #pragma unroll
    for (int i = 0; i < 4; ++i) {
      const int rowOut = bx * 32 + ty + i * 8;  // n (output col of Wv)
      wvt[(size_t)rowOut * D_DIM + colOut] = (short)f2bf(tile[tx][ty + i * 8]);
    }
  }
}

// ---------------- M^T GEMM (256 64x64 tiles, BK=64) + x split (4096), fused ----------------

__global__ __launch_bounds__(256) void k_m_cvtx(
    const short* __restrict__ wqh, const short* __restrict__ wql,
    const short* __restrict__ wkh, const short* __restrict__ wkl,
    short* __restrict__ mth, short* __restrict__ mtl,
    float* __restrict__ muSum,
    const float4* __restrict__ x,
    short* __restrict__ xh, short* __restrict__ xl)
{
  __shared__ alignas(16) short AsH[2][64][32];
  __shared__ alignas(16) short AsL[2][64][32];
  __shared__ alignas(16) short BsH[2][64][32];
  __shared__ alignas(16) short BsL[2][64][32];
  const int g = blockIdx.x;
  const int tid = threadIdx.x;

  if (g < 256) {
    // --- 64x64 M^T tile: A = Wk rows (e), B = Wq rows (d), inner = i ---
    floatx4 acc[2][2];
    const int blockM = (g >> 4) * 64;    // e
    const int blockN = (g & 15) * 64;    // d
    const int lane = tid & 63, wave = tid >> 6;
    const int wm = (wave >> 1) * 32, wn = (wave & 1) * 32;
    const int fm = lane & 15, fk = (lane >> 4) * 8;

    floatx4 zero = {0.f, 0.f, 0.f, 0.f};
    #pragma unroll
    for (int i = 0; i < 2; ++i)
      #pragma unroll
      for (int j = 0; j < 2; ++j)
        acc[i][j] = zero;

    const int sr = tid >> 2;             // row 0..63
    const int sc = (tid & 3) * 8;        // col 0..31 step 8
    const short* ah0 = wkh + (size_t)(blockM + sr) * D_DIM + sc;
    const short* al0 = wkl + (size_t)(blockM + sr) * D_DIM + sc;
    const short* bh0 = wqh + (size_t)(blockN + sr) * D_DIM + sc;
    const short* bl0 = wql + (size_t)(blockN + sr) * D_DIM + sc;
    short* ahB = &AsH[0][0][0]; short* alB = &AsL[0][0][0];
    short* bhB = &BsH[0][0][0]; short* blB = &BsL[0][0][0];
    const int l0 = tid * 8, l1 = (tid + 256) * 8;

    for (int kt = 0; kt < 16; ++kt) {    // BK=64
      const int kb = kt * 64;
      async_copy16(ah0 + kb, ahB + l0);
      async_copy16(ah0 + kb + 32, ahB + l1);
      async_copy16(al0 + kb, alB + l0);
      async_copy16(al0 + kb + 32, alB + l1);
      async_copy16(bh0 + kb, bhB + l0);
      async_copy16(bh0 + kb + 32, bhB + l1);
      async_copy16(bl0 + kb, blB + l0);
      async_copy16(bl0 + kb + 32, blB + l1);
      __syncthreads();
      #pragma unroll
      for (int ks = 0; ks < 2; ++ks) {
        bf16x8 ah[2], al[2], bh[2], bl[2];
        #pragma unroll
        for (int i = 0; i < 2; ++i) {
          ah[i] = *(const bf16x8*)(&AsH[ks][wm + i * 16 + fm][fk]);
          al[i] = *(const bf16x8*)(&AsL[ks][wm + i * 16 + fm][fk]);
        }
        #pragma unroll
        for (int j = 0; j < 2; ++j) {
          bh[j] = *(const bf16x8*)(&BsH[ks][wn + j * 16 + fm][fk]);
          bl[j] = *(const bf16x8*)(&BsL[ks][wn + j * 16 + fm][fk]);
        }
        #pragma unroll
        for (int i = 0; i < 2; ++i)
          #pragma unroll
          for (int j = 0; j < 2; ++j) {
            acc[i][j] = MFMA_BF16(ah[i], bh[j], acc[i][j], 0, 0, 0);
            acc[i][j] = MFMA_BF16(ah[i], bl[j], acc[i][j], 0, 0, 0);
            acc[i][j] = MFMA_BF16(al[i], bh[j], acc[i][j], 0, 0, 0);
          }
      }
      __syncthreads();
    }

    const int rb = wm + ((lane >> 4) << 2);
    const int cb = wn + (lane & 15);
    #pragma unroll
    for (int i = 0; i < 2; ++i)
      #pragma unroll
      for (int j = 0; j < 2; ++j) {
        const int n = blockN + cb + j * 16;
        #pragma unroll
        for (int r = 0; r < 2 * 2; ++r) {
          const int m = blockM + rb + i * 16 + r;
          const float f = acc[i][j][r];
          const unsigned short h = f2bf(f);
          mth[(size_t)m * D_DIM + n] = (short)h;
          mtl[(size_t)m * D_DIM + n] = (short)f2bf(f - bf2f(h));
        }
      }
    // mu partials: per row e, sum over this block's 64 d-cols
    #pragma unroll
    for (int i = 0; i < 2; ++i)
      #pragma unroll
      for (int r = 0; r < 4; ++r) {
        float v = acc[i][0][r] + acc[i][1][r];
        v += __shfl_xor(v, 1); v += __shfl_xor(v, 2);
        v += __shfl_xor(v, 4); v += __shfl_xor(v, 8);
        if ((lane & 15) == 0)
          atomicAdd(&muSum[blockM + rb + i * 16 + r], v);
      }
  } else {
    const size_t idx = (size_t)(g - 256) * 256 + tid;
    const float4 u4 = x[idx * 2];
    const float4 w4 = x[idx * 2 + 1];
    float f[8] = {u4.x, u4.y, u4.z, u4.w, w4.x, w4.y, w4.z, w4.w};
    short8v oh, ol;
    #pragma unroll
    for (int e = 0; e < 8; ++e) {
      const unsigned short h = f2bf(f[e]);
      oh[e] = (short)h;
      ol[e] = (short)f2bf(f[e] - bf2f(h));
    }
    *(short8v*)(xh + idx * 8) = oh;
    *(short8v*)(xl + idx * 8) = ol;
  }
}

// ---------------- per-row stats over reconstructed split-x ----------------

__global__ __launch_bounds__(256) void k_rowstats(
    const short* __restrict__ xh, const short* __restrict__ xl,
    const float* __restrict__ muSum, float* __restrict__ sq, float* __restrict__ u)
{
  const int r = blockIdx.x, tid = threadIdx.x;
  const ushort4 h = *(const ushort4*)(xh + (size_t)r * D_DIM + tid * 4);
  const ushort4 l = *(const ushort4*)(xl + (size_t)r * D_DIM + tid * 4);
  const float4 m4 = *(const float4*)(muSum + tid * 4);
  const float x0 = bf2f(h.x) + bf2f(l.x);
  const float x1 = bf2f(h.y) + bf2f(l.y);
  const float x2 = bf2f(h.z) + bf2f(l.z);
  const float x3 = bf2f(h.w) + bf2f(l.w);
  float s = x0 + x1 + x2 + x3;
  float uu = m4.x * x0 + m4.y * x1 + m4.z * x2 + m4.w * x3;
  #pragma unroll
  for (int off = 32; off > 0; off >>= 1) {
    s  += __shfl_xor(s, off);
    uu += __shfl_xor(uu, off);
  }
  __shared__ float ps[4], pu[4];
  if ((tid & 63) == 0) { ps[tid >> 6] = s; pu[tid >> 6] = uu; }
  __syncthreads();
  if (tid == 0) {
    sq[r] = ps[0] + ps[1] + ps[2] + ps[3];
    u[r]  = (pu[0] + pu[1] + pu[2] + pu[3]) * (1.0f / 1024.0f);
  }
}

// ---------------- N~ = x M - sq mu^T, 256x128 tiles, dbuf phased core ----------------
// 256 blocks = exactly 1 block/CU machine fill.

__global__ __launch_bounds__(512) void k_gemm_n8(
    const short* __restrict__ xh, const short* __restrict__ xl,
    const short* __restrict__ mth, const short* __restrict__ mtl,
    const float* __restrict__ sq, const float* __restrict__ muSum,
    short* __restrict__ nh, short* __restrict__ nl)
{
  __shared__ alignas(16) short AsH[2][256][32];
  __shared__ alignas(16) short AsL[2][256][32];
  __shared__ alignas(16) short BsH[2][128][32];
  __shared__ alignas(16) short BsL[2][128][32];
  floatx4 acc[4][4];
  const int g = blockIdx.x;
  const int swz = (g & 7) * 32 + (g >> 3);     // XCD-contiguous chunks
  const int blockM = (swz >> 3) * 256;         // global row (b,s)
  const int blockN = (swz & 7) * 128;          // e
  split_core8(xh, xl, mth, mtl, D_DIM, D_DIM, D_DIM / 32,
              blockM, blockN, AsH, AsL, BsH, BsL, acc);

  const int tid = threadIdx.x, lane = tid & 63, wave = tid >> 6;
  const int wm = (wave >> 1) * 64, wn = (wave & 1) * 64;
  const int rb = wm + ((lane >> 4) << 2);
  const int cb = wn + (lane & 15);
  #pragma unroll
  for (int i = 0; i < 4; ++i)
    #pragma unroll
    for (int j = 0; j < 4; ++j) {
      const int n = blockN + cb + j * 16;
      const float muv = muSum[n] * (1.0f / 1024.0f);
      #pragma unroll
      for (int r = 0; r < 4; ++r) {
        const int m = blockM + rb + i * 16 + r;
        const float f = acc[i][j][r] - sq[m] * muv;   // deflate
        const unsigned short h = f2bf(f);
        nh[(size_t)m * D_DIM + n] = (short)h;
        nl[(size_t)m * D_DIM + n] = (short)f2bf(f - bf2f(h));
      }
    }
}

// ---------------- fused scores + V, persistent 256-block work queue ----------------
// items 0..287: score tiles (256x128, lower-tri, heavy — drained first);
//               epilogue stores BAND-GUARDED ((n>>7)<=(m>>7)) so the dead
//               zone is never touched by raw scores.
// items 288..543: V tiles (256x128, light — tail fillers; also zero-fill
//                 a disjoint 32-row slice of attn's strict upper tri —
//                 sole writer of that region, no ordering hazard)

__global__ __launch_bounds__(512) void k_gemm_sv8(
    const short* __restrict__ nh, const short* __restrict__ nl,
    const short* __restrict__ xh, const short* __restrict__ xl,
    const float* __restrict__ sq, const float* __restrict__ u,
    const short* __restrict__ wvt, float* __restrict__ attn,
    short* __restrict__ vt, int* __restrict__ cnt)
{
  __shared__ alignas(16) short AsH[2][256][32];
  __shared__ alignas(16) short AsL[2][256][32];
  __shared__ alignas(16) short BsH[2][128][32];
  __shared__ alignas(16) short BsL[2][128][32];
  __shared__ int s_item;

  const int tid = threadIdx.x, lane = tid & 63, wave = tid >> 6;
  const int wm = (wave >> 1) * 64, wn = (wave & 1) * 64;
  const int rb = wm + ((lane >> 4) << 2);
  const int cb = wn + (lane & 15);

  for (;;) {
    if (tid == 0) s_item = atomicAdd(cnt, 1);
    __syncthreads();
    const int item = s_item;
    if (item >= 544) return;     // block-uniform exit

    floatx4 acc[4][4];
    if (item < 288) {
      // scores: per batch, lower-tri tiles of 256 rows x 128 cols:
      // bi in [0,8), bj in [0, 2*bi+2). 72/batch.
      const int b = item / 72;
      int t = item - b * 72;
      int bi = 0;
      while (t >= 2 * bi + 2) { t -= 2 * bi + 2; ++bi; }
      const int bj = t;

      const size_t boff = (size_t)b * S_LEN * D_DIM;
      split_core8(nh + boff, nl + boff, xh + boff, xl + boff,
                  D_DIM, D_DIM, D_DIM / 32, bi * 256, bj * 128,
                  AsH, AsL, BsH, BsL, acc);

      float* out = attn + (size_t)b * S_LEN * S_LEN;
      const int rowBase = (b << 11) + bi * 256;
      const int colBase = (b << 11) + bj * 128;
      #pragma unroll
      for (int j = 0; j < 4; ++j) {
        const int n = bj * 128 + cb + j * 16;
        const float uv = u[colBase + cb + j * 16];
        const int nt = n >> 7;                    // col 128-tile index
        #pragma unroll
        for (int i = 0; i < 4; ++i)
          #pragma unroll
          for (int r = 0; r < 4; ++r) {
            const int m = bi * 256 + rb + i * 16 + r;
            if (nt <= (m >> 7)) {                 // within causal band only
              const float sv = sq[rowBase + rb + i * 16 + r];
              out[(size_t)m * S_LEN + n] = acc[i][j][r] + sv * uv;  // raw
            }
          }
      }
    } else {
      const int vb = item - 288;            // 0..255
      const int blockM = (vb >> 3) * 256;   // global row over 8192
      const int blockN = (vb & 7) * 128;    // d
      single_core8(xh, wvt, D_DIM, D_DIM, D_DIM / 32, blockM, blockN,
                   AsH, BsH, acc);
      #pragma unroll
      for (int i = 0; i < 4; ++i)
        #pragma unroll
        for (int j = 0; j < 4; ++j) {
          const int n = blockN + cb + j * 16;   // d index
          const int m0 = blockM + rb + i * 16;  // global row, 4-aligned
          const int b = m0 >> 11;
          const int s0 = m0 & (S_LEN - 1);
          ushort4 pk;
          pk.x = f2bf(acc[i][j][0]); pk.y = f2bf(acc[i][j][1]);
          pk.z = f2bf(acc[i][j][2]); pk.w = f2bf(acc[i][j][3]);
          *(ushort4*)(vt + ((size_t)b * D_DIM + n) * S_LEN + s0) = pk;
        }

      // zero-fill strict upper block-tri of attn for this tile's 32-row
      // slice: rows partitioned by d-index (vb&7), coverage exact over
      // all 8192 rows. Row s zeroes cols [((s>>7)+1)<<7, 2048).
      {
        const int bZ = blockM >> 11;                       // batch
        const int sBase = (blockM & (S_LEN - 1)) + (vb & 7) * 32;
        float* arow = attn + (size_t)bZ * S_LEN * S_LEN;
        const int rr = tid >> 4;                           // 0..31
        const int cc = tid & 15;                           // 0..15
        const int s = sBase + rr;
        const int kb0 = ((s >> 7) + 1) << 7;
        const floatx4 z4 = {0.f, 0.f, 0.f, 0.f};
        float* rp = arow + (size_t)s * S_LEN;
        for (int c = kb0 + cc * 4; c < S_LEN; c += 64)
          *(floatx4*)(rp + c) = z4;
      }
    }
  }
}

// ---------------- softmax: prefix-only reads, band-limited writes ----------------
// Upper-tri zeros are pre-written by sv8's V branch (sole writer); both
// f32 and pb writes are limited to the 128-aligned live band.

__global__ __launch_bounds__(256) void k_softmax(float* __restrict__ attn,
                                                 short* __restrict__ pb) {
  const int b = blockIdx.x >> 11;
  const int q = blockIdx.x & (S_LEN - 1);
  float* row  = attn + ((size_t)b * S_LEN + q) * S_LEN;
  short* prow = pb   + ((size_t)b * S_LEN + q) * S_LEN;
  const int tid = threadIdx.x;
  const int k0 = tid * 8;
  const int kBand = ((q >> 7) + 1) << 7;   // 128-aligned band end
  __shared__ float sMax[4], sSum[4];

  float v[8];
  if (k0 <= q) {               // load only the live prefix
    const float4 a0 = *(const float4*)(row + k0);
    const float4 a1 = *(const float4*)(row + k0 + 4);
    v[0] = a0.x; v[1] = a0.y; v[2] = a0.z; v[3] = a0.w;
    v[4] = a1.x; v[5] = a1.y; v[6] = a1.z; v[7] = a1.w;
  } else {
    #pragma unroll
    for (int e = 0; e < 8; ++e) v[e] = -3.0e38f;
  }

  float mx = -3.0e38f;
  #pragma unroll
  for (int e = 0; e < 8; ++e) {
    v[e] = (k0 + e <= q) ? v[e] : -3.0e38f;
    mx = fmaxf(mx, v[e]);
  }
  #pragma unroll
  for (int off = 32; off > 0; off >>= 1) mx = fmaxf(mx, __shfl_xor(mx, off));
  if ((tid & 63) == 0) sMax[tid >> 6] = mx;
  __syncthreads();
  mx = fmaxf(fmaxf(sMax[0], sMax[1]), fmaxf(sMax[2], sMax[3]));

  float s = 0.f;
  #pragma unroll
  for (int e = 0; e < 8; ++e) {
    const float p = (k0 + e <= q) ? __expf((v[e] - mx) * 0.03125f) : 0.f;
    v[e] = p;
    s += p;
  }
  #pragma unroll
  for (int off = 32; off > 0; off >>= 1) s += __shfl_xor(s, off);
  if ((tid & 63) == 0) sSum[tid >> 6] = s;
  __syncthreads();
  s = sSum[0] + sSum[1] + sSum[2] + sSum[3];
  const float inv = 1.0f / s;

  float o[8];
  #pragma unroll
  for (int e = 0; e < 8; ++e) o[e] = v[e] * inv;   // 0 for masked
  if (k0 < kBand) {
    float4 w0 = {o[0], o[1], o[2], o[3]};
    float4 w1 = {o[4], o[5], o[6], o[7]};
    *(float4*)(row + k0) = w0;
    *(float4*)(row + k0 + 4) = w1;
    ushort4 p0, p1;
    p0.x = f2bf(o[0]); p0.y = f2bf(o[1]); p0.z = f2bf(o[2]); p0.w = f2bf(o[3]);
    p1.x = f2bf(o[4]); p1.y = f2bf(o[5]); p1.z = f2bf(o[6]); p1.w = f2bf(o[7]);
    *(ushort4*)(prow + k0) = p0;
    *(ushort4*)(prow + k0 + 4) = p1;
  }
}

// ---------------- context = P @ V, 128^2, BK=64 k-plane LDS, swizzled ----------------
// T2 swizzle (rule 21, both-sides): source col unit pre-swizzled
// su = (u0 ^ ((r0>>1)&3))*8 with linear gload_lds dest; frag reads use
// the same XOR. Old unswizzled reads were an 8-way bank conflict.

__global__ __launch_bounds__(256) void k_gemm_ctx(
    const short* __restrict__ pb, const short* __restrict__ vt,
    float* __restrict__ ctx)
{
  __shared__ alignas(16) short As2[2][128][32];
  __shared__ alignas(16) short Bs2[2][128][32];
  floatx4 acc[4][4];
  const int b = blockIdx.z;
  const int by = 15 - blockIdx.y;        // heavy K-loops dispatched first
  const int blockM = by * 128;           // q
  const int blockN = blockIdx.x * 128;   // d
  const int kIters = (by + 1) * 2;       // BK=64; k <= blockM+127 only
  const short* A = pb + (size_t)b * S_LEN * S_LEN;
  const short* B = vt + (size_t)b * D_DIM * S_LEN;

  const int tid = threadIdx.x, lane = tid & 63, wave = tid >> 6;
  const int wm = (wave >> 1) * 64, wn = (wave & 1) * 64;
  const int fm = lane & 15;
  const int fu = lane >> 4;

  int rA[4], sA[4], rB[4], sB[4];
  #pragma unroll
  for (int i = 0; i < 4; ++i) {
    rA[i] = wm + i * 16 + fm;
    sA[i] = (fu ^ ((rA[i] >> 1) & 3)) * 8;
    rB[i] = wn + i * 16 + fm;
    sB[i] = (fu ^ ((rB[i] >> 1) & 3)) * 8;
  }

  floatx4 zero = {0.f, 0.f, 0.f, 0.f};
  #pragma unroll
  for (int i = 0; i < 4; ++i)
    #pragma unroll
    for (int j = 0; j < 4; ++j)
      acc[i][j] = zero;

  const int r0 = tid >> 2;               // 0..63
  const int u0 = tid & 3;
  const int su = (u0 ^ ((r0 >> 1) & 3)) * 8;   // pre-swizzled source unit
  // rows r0 and r0+64 share ((row>>1)&3) (64/2 = 32, 32%4 == 0) -> same su
  const short* a0 = A + (size_t)(blockM + r0) * S_LEN + su;
  const short* a1 = a0 + (size_t)64 * S_LEN;
  const short* b0 = B + (size_t)(blockN + r0) * S_LEN + su;
  const short* b1 = b0 + (size_t)64 * S_LEN;
  short* asBase = &As2[0][0][0];
  short* bsBase = &Bs2[0][0][0];
  short* as0 = asBase + (size_t)tid * 8;             // [0][r0][u0*8]
  short* as1 = asBase + (size_t)(tid + 256) * 8;     // [0][r0+64][u0*8]
  short* as2 = asBase + (size_t)(tid + 512) * 8;     // [1][r0][u0*8]
  short* as3 = asBase + (size_t)(tid + 768) * 8;     // [1][r0+64][u0*8]
  short* bs0 = bsBase + (size_t)tid * 8;
  short* bs1 = bsBase + (size_t)(tid + 256) * 8;
  short* bs2 = bsBase + (size_t)(tid + 512) * 8;
  short* bs3 = bsBase + (size_t)(tid + 768) * 8;

  for (int kt = 0; kt < kIters; ++kt) {
    const int kb = kt * 64;
    async_copy16(a0 + kb, as0);
    async_copy16(a1 + kb, as1);
    async_copy16(a0 + kb + 32, as2);
    async_copy16(a1 + kb + 32, as3);
    async_copy16(b0 + kb, bs0);
    async_copy16(b1 + kb, bs1);
    async_copy16(b0 + kb + 32, bs2);
    async_copy16(b1 + kb + 32, bs3);
    __syncthreads();
    #pragma unroll
    for (int ks = 0; ks < 2; ++ks) {
      bf16x8 af[4], bfr[4];
      #pragma unroll
      for (int i = 0; i < 4; ++i)
        af[i] = *(const bf16x8*)(&As2[ks][rA[i]][sA[i]]);
      #pragma unroll
      for (int j = 0; j < 4; ++j)
        bfr[j] = *(const bf16x8*)(&Bs2[ks][rB[j]][sB[j]]);
      __builtin_amdgcn_s_setprio(1);
      #pragma unroll
      for (int i = 0; i < 4; ++i)
        #pragma unroll
        for (int j = 0; j < 4; ++j)
          acc[i][j] = MFMA_BF16(af[i], bfr[j], acc[i][j], 0, 0, 0);
      __builtin_amdgcn_s_setprio(0);
    }
    __syncthreads();
  }

  float* out = ctx + (size_t)b * S_LEN * D_DIM;
  const int rb = wm + ((lane >> 4) << 2);
  const int cb = wn + (lane & 15);
  #pragma unroll
  for (int i = 0; i < 4; ++i)
    #pragma unroll
    for (int j = 0; j < 4; ++j) {
      const int n = blockN + cb + j * 16;
      #pragma unroll
      for (int r = 0; r < 4; ++r) {
        const int m = blockM + rb + i * 16 + r;
        out[(size_t)m * D_DIM + n] = acc[i][j][r];
      }
    }
}

// ---------------- launch ----------------

extern "C" void kernel_launch(void* const* d_in, const int* in_sizes, int n_in,
                              void* d_out, int out_size, void* d_ws, size_t ws_size,
                              hipStream_t stream) {
  const float* x  = (const float*)d_in[0];
  const float* wq = (const float*)d_in[1];
  const float* wk = (const float*)d_in[2];
  const float* wv = (const float*)d_in[3];

  float* out  = (float*)d_out;
  float* ctx  = out;                                       // [4,2048,1024]
  float* attn = out + (size_t)NBATCH * S_LEN * D_DIM;      // [4,2048,2048]

  // workspace (shorts), ~94 MiB; pb aliases nh/nl (dead after scores GEMM)
  short* ws  = (short*)d_ws;
  short* xh  = ws;                                  // 8M
  short* xl  = xh + (size_t)8 * MEG;                // 8M
  short* wqh = xl + (size_t)8 * MEG;                // 1M Wq hi (original layout)
  short* wql = wqh + (size_t)1 * MEG;               // 1M Wq lo
  short* wkh = wql + (size_t)1 * MEG;               // 1M Wk hi
  short* wkl = wkh + (size_t)1 * MEG;               // 1M Wk lo
  short* wvt = wkl + (size_t)1 * MEG;               // 1M Wv^T hi
  short* mth = wvt + (size_t)1 * MEG;               // 1M M^T hi
  short* mtl = mth + (size_t)1 * MEG;               // 1M M^T lo
  short* nh  = mtl + (size_t)1 * MEG;               // 8M N~ hi
  short* nl  = nh + (size_t)8 * MEG;                // 8M N~ lo
  short* vt  = nl + (size_t)8 * MEG;                // 8M V^T [b,d,s]
  short* pb  = nh;                                  // 16M alias (nh+nl)
  float* fb  = (float*)(vt + (size_t)8 * MEG);
  float* muS = fb;                                  // 1024 (sum over d, not mean)
  float* sq  = fb + 1024;                           // 8192
  float* u   = sq + 8192;                           // 8192
  int*   cnt = (int*)(u + 8192);                    // sv8 work-queue counter

  k_cvt_w<<<2048, 256, 0, stream>>>(wq, wk, wv, wqh, wql, wkh, wkl, wvt,
                                    muS, cnt);
  k_m_cvtx<<<4352, 256, 0, stream>>>(wqh, wql, wkh, wkl, mth, mtl, muS,
                                     (const float4*)x, xh, xl);
  k_rowstats<<<8192, 256, 0, stream>>>(xh, xl, muS, sq, u);
  k_gemm_n8<<<256, 512, 0, stream>>>(xh, xl, mth, mtl, sq, muS, nh, nl);
  k_gemm_sv8<<<256, 512, 0, stream>>>(nh, nl, xh, xl, sq, u, wvt, attn,
                                      vt, cnt);
  k_softmax<<<NBATCH * S_LEN, 256, 0, stream>>>(attn, pb);
  k_gemm_ctx<<<dim3(8, 16, 4), 256, 0, stream>>>(pb, vt, ctx);
}